// Round 3
// baseline (9126.855 us; speedup 1.0000x reference)
//
#include <hip/hip_runtime.h>
#include <cmath>
#include <cstdint>

#define D_FEAT 6
#define T_SEQ  60
#define HID    256
#define G3     768
#define NROW   2048
#define NSAMP  20480

__device__ __forceinline__ float sigmoidf_(float x) { return 1.0f / (1.0f + expf(-x)); }

// ---------------------------------------------------------------- weight prep
struct PrepArgs {
  const float* src[5];
  float* dst[5];
  int N[5], K[5];
};

__global__ void prep_weights(PrepArgs a) {
  int seg = blockIdx.y;
  const float* S = a.src[seg];
  float* D = a.dst[seg];
  int N = a.N[seg], K = a.K[seg];
  int total = N * K;
  for (int i = blockIdx.x * blockDim.x + threadIdx.x; i < total; i += gridDim.x * blockDim.x) {
    int n = i / K, k = i - n * K;
    D[(size_t)k * N + n] = S[i];   // WT[k][n] = W[n][k]
  }
}

// Gate-packed GRU weights: P0[k][j][3] (k<256) from Whh0; P1[k][j][3] (k<512) from [Wih1;Whh1]
__global__ void prep_packed(const float* __restrict__ Whh0, const float* __restrict__ Wih1,
                            const float* __restrict__ Whh1, float* __restrict__ P0,
                            float* __restrict__ P1) {
  int i = blockIdx.x * 256 + threadIdx.x;
  if (i < 196608) {   // 256*256*3
    int k = i / 768, r = i - k * 768, jj = r / 3, g = r - jj * 3;
    P0[i] = Whh0[(size_t)(g * 256 + jj) * 256 + k];
  }
  if (i < 393216) {   // 512*256*3
    int k = i / 768, r = i - k * 768, jj = r / 3, g = r - jj * 3;
    P1[i] = (k < 256) ? Wih1[(size_t)(g * 256 + jj) * 256 + k]
                      : Whh1[(size_t)(g * 256 + jj) * 256 + (k - 256)];
  }
}

// ---------------------------------------------------------------- GRU layer 0 step (transposed h)
// hT layout: [k][m] = [256][2048]. Thread (tx=j-lane, ty): rows m0..m0+3, col j.
__global__ __launch_bounds__(256, 2)
void gru0_step(const float* __restrict__ hTprev, float* __restrict__ hTout,
               const float* __restrict__ inp, const float* __restrict__ P0,
               const float* __restrict__ Wih, const float* __restrict__ bih,
               const float* __restrict__ bhh, int t)
{
  const int tx = threadIdx.x, ty = threadIdx.y;
  const int j = blockIdx.x * 32 + tx;
  const int m0 = blockIdx.y * 32 + ty * 4;

  float accr[4] = {0,0,0,0}, accz[4] = {0,0,0,0}, accn[4] = {0,0,0,0};
  const float* pA = hTprev + m0;       // + k*2048
  const float* pB = P0 + j * 3;        // + k*768

  float4 Abuf[2][4];
  float  Bbuf[2][12];

  auto load_grp = [&](int buf, int kb) {
#pragma unroll
    for (int u = 0; u < 4; ++u) {
      Abuf[buf][u] = *(const float4*)(pA + (size_t)(kb + u) * 2048);
      Bbuf[buf][u*3+0] = pB[(size_t)(kb + u) * 768 + 0];
      Bbuf[buf][u*3+1] = pB[(size_t)(kb + u) * 768 + 1];
      Bbuf[buf][u*3+2] = pB[(size_t)(kb + u) * 768 + 2];
    }
  };
  auto fma_grp = [&](int buf) {
#pragma unroll
    for (int u = 0; u < 4; ++u) {
      float4 a = Abuf[buf][u];
      float br = Bbuf[buf][u*3], bz = Bbuf[buf][u*3+1], bn = Bbuf[buf][u*3+2];
      accr[0] += a.x*br; accz[0] += a.x*bz; accn[0] += a.x*bn;
      accr[1] += a.y*br; accz[1] += a.y*bz; accn[1] += a.y*bn;
      accr[2] += a.z*br; accz[2] += a.z*bz; accn[2] += a.z*bn;
      accr[3] += a.w*br; accz[3] += a.w*bz; accn[3] += a.w*bn;
    }
  };

  load_grp(0, 0);
  for (int kb = 0; kb < 256; kb += 8) {
    load_grp(1, (kb + 4 < 256) ? kb + 4 : 0);
    fma_grp(0);
    load_grp(0, (kb + 8 < 256) ? kb + 8 : 0);
    fma_grp(1);
  }

  float bhr = bhh[j], bhz = bhh[256 + j], bhn = bhh[512 + j];
  float4 hold = *(const float4*)(hTprev + (size_t)j * 2048 + m0);
  float hnew[4];
#pragma unroll
  for (int r = 0; r < 4; ++r) {
    int row = m0 + r;
    float xw[3];
#pragma unroll
    for (int g = 0; g < 3; ++g) {
      const float* wi = Wih + (size_t)(g * 256 + j) * D_FEAT;
      float s = bih[g * 256 + j];
#pragma unroll
      for (int i = 0; i < D_FEAT; ++i)
        s += inp[(size_t)row * (D_FEAT * T_SEQ) + i * T_SEQ + t] * wi[i];
      xw[g] = s;
    }
    float rr = sigmoidf_(xw[0] + accr[r] + bhr);
    float zz = sigmoidf_(xw[1] + accz[r] + bhz);
    float nn = tanhf(xw[2] + rr * (accn[r] + bhn));
    float ho = ((const float*)&hold)[r];
    hnew[r] = (1.f - zz) * nn + zz * ho;
  }
  *(float4*)(hTout + (size_t)j * 2048 + m0) = *(float4*)hnew;
}

// ---------------------------------------------------------------- GRU layer 1 step (transposed)
__global__ __launch_bounds__(256, 2)
void gru1_step(const float* __restrict__ xT, const float* __restrict__ hTprev,
               float* __restrict__ hTout, const float* __restrict__ P1,
               const float* __restrict__ bih, const float* __restrict__ bhh)
{
  const int tx = threadIdx.x, ty = threadIdx.y;
  const int j = blockIdx.x * 32 + tx;
  const int m0 = blockIdx.y * 32 + ty * 4;

  float accr[4] = {0,0,0,0}, accz[4] = {0,0,0,0};
  float accxn[4] = {0,0,0,0}, acchn[4] = {0,0,0,0};
  const float* pB = P1 + j * 3;        // + k*768, k in [0,512)

  float4 Abuf[2][4];
  float  Bbuf[2][12];

  // ---- phase 1: k 0..255 over xT, n-gate -> accxn
  {
    const float* pA = xT + m0;
    auto load_grp = [&](int buf, int kb) {
#pragma unroll
      for (int u = 0; u < 4; ++u) {
        Abuf[buf][u] = *(const float4*)(pA + (size_t)(kb + u) * 2048);
        Bbuf[buf][u*3+0] = pB[(size_t)(kb + u) * 768 + 0];
        Bbuf[buf][u*3+1] = pB[(size_t)(kb + u) * 768 + 1];
        Bbuf[buf][u*3+2] = pB[(size_t)(kb + u) * 768 + 2];
      }
    };
    auto fma_grp = [&](int buf) {
#pragma unroll
      for (int u = 0; u < 4; ++u) {
        float4 a = Abuf[buf][u];
        float br = Bbuf[buf][u*3], bz = Bbuf[buf][u*3+1], bn = Bbuf[buf][u*3+2];
        accr[0] += a.x*br; accz[0] += a.x*bz; accxn[0] += a.x*bn;
        accr[1] += a.y*br; accz[1] += a.y*bz; accxn[1] += a.y*bn;
        accr[2] += a.z*br; accz[2] += a.z*bz; accxn[2] += a.z*bn;
        accr[3] += a.w*br; accz[3] += a.w*bz; accxn[3] += a.w*bn;
      }
    };
    load_grp(0, 0);
    for (int kb = 0; kb < 256; kb += 8) {
      load_grp(1, (kb + 4 < 256) ? kb + 4 : 0);
      fma_grp(0);
      load_grp(0, (kb + 8 < 256) ? kb + 8 : 0);
      fma_grp(1);
    }
  }
  // ---- phase 2: k 256..511 over hTprev, n-gate -> acchn
  {
    const float* pA = hTprev + m0;
    const float* pB2 = pB + (size_t)256 * 768;
    auto load_grp = [&](int buf, int kb) {
#pragma unroll
      for (int u = 0; u < 4; ++u) {
        Abuf[buf][u] = *(const float4*)(pA + (size_t)(kb + u) * 2048);
        Bbuf[buf][u*3+0] = pB2[(size_t)(kb + u) * 768 + 0];
        Bbuf[buf][u*3+1] = pB2[(size_t)(kb + u) * 768 + 1];
        Bbuf[buf][u*3+2] = pB2[(size_t)(kb + u) * 768 + 2];
      }
    };
    auto fma_grp = [&](int buf) {
#pragma unroll
      for (int u = 0; u < 4; ++u) {
        float4 a = Abuf[buf][u];
        float br = Bbuf[buf][u*3], bz = Bbuf[buf][u*3+1], bn = Bbuf[buf][u*3+2];
        accr[0] += a.x*br; accz[0] += a.x*bz; acchn[0] += a.x*bn;
        accr[1] += a.y*br; accz[1] += a.y*bz; acchn[1] += a.y*bn;
        accr[2] += a.z*br; accz[2] += a.z*bz; acchn[2] += a.z*bn;
        accr[3] += a.w*br; accz[3] += a.w*bz; acchn[3] += a.w*bn;
      }
    };
    load_grp(0, 0);
    for (int kb = 0; kb < 256; kb += 8) {
      load_grp(1, (kb + 4 < 256) ? kb + 4 : 0);
      fma_grp(0);
      load_grp(0, (kb + 8 < 256) ? kb + 8 : 0);
      fma_grp(1);
    }
  }

  float bir = bih[j] + bhh[j];
  float biz = bih[256 + j] + bhh[256 + j];
  float bixn = bih[512 + j], bhn = bhh[512 + j];
  float4 hold = *(const float4*)(hTprev + (size_t)j * 2048 + m0);
  float hnew[4];
#pragma unroll
  for (int r = 0; r < 4; ++r) {
    float rr = sigmoidf_(accr[r] + bir);
    float zz = sigmoidf_(accz[r] + biz);
    float nn = tanhf((accxn[r] + bixn) + rr * (acchn[r] + bhn));
    float ho = ((const float*)&hold)[r];
    hnew[r] = (1.f - zz) * nn + zz * ho;
  }
  *(float4*)(hTout + (size_t)j * 2048 + m0) = *(float4*)hnew;
}

// transpose [256][2048] -> [2048][256]
__global__ void transpose_kT(const float* __restrict__ in, float* __restrict__ out) {
  __shared__ float tile[32][33];
  const int mb = blockIdx.x * 32;
  const int kb = blockIdx.y * 32;
  const int tx = threadIdx.x & 31, tyy = threadIdx.x >> 5;
  for (int r = tyy; r < 32; r += 8)
    tile[r][tx] = in[(size_t)(kb + r) * 2048 + mb + tx];
  __syncthreads();
  for (int r = tyy; r < 32; r += 8)
    out[(size_t)(mb + r) * 256 + kb + tx] = tile[tx][r];
}

// ---------------------------------------------------------------- generic GEMM
__global__ __launch_bounds__(256, 2)
void gemm_act(const float* __restrict__ A, const int* __restrict__ rowsrc,
              const float* __restrict__ WT, const float* __restrict__ bias,
              float* __restrict__ C, int M, int N, int K, int act)
{
  __shared__ float4 As4[128 * 32];
  const int tx = threadIdx.x, ty = threadIdx.y;
  const int tid = ty * 32 + tx;
  const int n0 = blockIdx.x * 32, m0 = blockIdx.y * 32;
  const int K4 = K >> 2;

  for (int c = tid; c < K4 * 32; c += 256) {
    int k4 = c % K4, m = c / K4;
    int row = m0 + m;
    if (rowsrc) row = rowsrc[row];
    As4[k4 * 32 + m] = *(const float4*)(A + (size_t)row * K + k4 * 4);
  }
  __syncthreads();

  float acc[4] = {0,0,0,0};
  const int n = n0 + tx;
  const float* pb = WT + n;

  float bc[4], bn_[4];
#pragma unroll
  for (int kk = 0; kk < 4; ++kk) bc[kk] = pb[(size_t)kk * N];
  for (int k4 = 0; k4 < K4; ++k4) {
    int nk4 = (k4 + 1 < K4) ? (k4 + 1) : 0;
    const float* pn = pb + (size_t)nk4 * 4 * N;
#pragma unroll
    for (int kk = 0; kk < 4; ++kk) bn_[kk] = pn[(size_t)kk * N];
    float4 a0 = As4[k4 * 32 + ty * 4 + 0];
    float4 a1 = As4[k4 * 32 + ty * 4 + 1];
    float4 a2 = As4[k4 * 32 + ty * 4 + 2];
    float4 a3 = As4[k4 * 32 + ty * 4 + 3];
#pragma unroll
    for (int kk = 0; kk < 4; ++kk) {
      float b = bc[kk];
      acc[0] += ((const float*)&a0)[kk] * b;
      acc[1] += ((const float*)&a1)[kk] * b;
      acc[2] += ((const float*)&a2)[kk] * b;
      acc[3] += ((const float*)&a3)[kk] * b;
    }
#pragma unroll
    for (int q = 0; q < 4; ++q) bc[q] = bn_[q];
  }
  float bb = bias ? bias[n] : 0.f;
#pragma unroll
  for (int r = 0; r < 4; ++r) {
    float v = acc[r] + bb;
    if (act) v = (v >= 0.f) ? v : 0.01f * v;
    C[(size_t)(m0 + ty * 4 + r) * N + n] = v;
  }
}

// ---------------------------------------------------------------- small stages
__global__ void mbday_part(const float* __restrict__ mbf, float* __restrict__ part) {
  int d = blockIdx.x, sl = blockIdx.y, c = threadIdx.x;
  float s = 0.f;
  int base = d * 512 + sl * 64;
  for (int st = 0; st < 64; ++st) s += mbf[(size_t)(base + st) * 256 + c];
  part[(size_t)(d * 8 + sl) * 256 + c] = s;
}

__global__ void mbday_fin(const float* __restrict__ part, float* __restrict__ mbday) {
  int d = blockIdx.x, c = threadIdx.x;
  float s = 0.f;
#pragma unroll
  for (int p = 0; p < 8; ++p) s += part[(size_t)(d * 8 + p) * 256 + c];
  mbday[d * 256 + c] = s * (1.0f / 512.0f);
}

__global__ void daytopk_kernel(const float* __restrict__ mbday, const float* __restrict__ thd,
                               int* __restrict__ dayidx) {
  __shared__ float mbs[256];
  __shared__ float sim[256];
  __shared__ float red[256];
  __shared__ int   redi[256];
  const int d = blockIdx.x, t = threadIdx.x;
  mbs[t] = mbday[d * 256 + t];
  __syncthreads();
  red[t] = mbs[t] * mbs[t];
  __syncthreads();
  for (int o = 128; o; o >>= 1) { if (t < o) red[t] += red[t + o]; __syncthreads(); }
  float xn = sqrtf(red[0]);
  float v = -INFINITY;
  if (t < 240) {
    float dot = 0.f, yn2 = 0.f;
    for (int k = 0; k < 256; ++k) {
      float y = thd[t * 256 + k];
      dot += mbs[k] * y;
      yn2 += y * y;
    }
    float den = xn * sqrtf(yn2);
    v = (den > 0.f) ? dot / den : 0.f;
  }
  sim[t] = v;
  __syncthreads();
  for (int it = 0; it < 10; ++it) {
    red[t] = sim[t]; redi[t] = t;
    __syncthreads();
    for (int o = 128; o; o >>= 1) {
      if (t < o) {
        if (red[t + o] > red[t] || (red[t + o] == red[t] && redi[t + o] < redi[t])) {
          red[t] = red[t + o]; redi[t] = redi[t + o];
        }
      }
      __syncthreads();
    }
    if (t == 0) { int bi = redi[0]; dayidx[d * 10 + it] = bi; sim[bi] = -INFINITY; }
    __syncthreads();
  }
}

__global__ void rowsrc_kernel(const int* __restrict__ dayidx, int* __restrict__ rowsrc) {
  int r = blockIdx.x * 256 + threadIdx.x;
  if (r < NSAMP) rowsrc[r] = dayidx[r >> 9] * 512 + (r & 511);
}

__global__ void rownorm_kernel(const float* __restrict__ X, float* __restrict__ out, int rows) {
  int w = threadIdx.x >> 6;
  int lane = threadIdx.x & 63;
  int row = blockIdx.x * 4 + w;
  if (row >= rows) return;
  float4 x = *(const float4*)(X + (size_t)row * 256 + lane * 4);
  float s = x.x * x.x + x.y * x.y + x.z * x.z + x.w * x.w;
#pragma unroll
  for (int o = 32; o; o >>= 1) s += __shfl_down(s, o, 64);
  if (lane == 0) out[row] = sqrtf(s);
}

__global__ void qnorm_kernel(float* __restrict__ q, const float* __restrict__ qn) {
  int i = blockIdx.x * 256 + threadIdx.x;
  int row = i >> 8;
  float n = qn[row];
  q[i] = (n > 0.f) ? q[i] / n : 0.f;
}

__global__ void khT_kernel(const float* __restrict__ kh, const float* __restrict__ khn,
                           float* __restrict__ khT) {
  __shared__ float tile[32][33];
  int jb = blockIdx.x * 32;
  int kb = blockIdx.y * 32;
  int tx = threadIdx.x & 31, tyy = threadIdx.x >> 5;
  for (int rr = tyy; rr < 32; rr += 8) {
    float n = khn[jb + rr];
    float v = kh[(size_t)(jb + rr) * 256 + kb + tx];
    tile[rr][tx] = (n > 0.f) ? v / n : 0.f;
  }
  __syncthreads();
  for (int rr = tyy; rr < 32; rr += 8) {
    khT[(size_t)(kb + rr) * NSAMP + jb + tx] = tile[tx][rr];
  }
}

// ---------------------------------------------------------------- cs GEMM + top-10 (split, XCD-swizzled)
__global__ __launch_bounds__(256, 4)
void csmax_kernel(const float* __restrict__ qh, const float* __restrict__ khT,
                  float* __restrict__ topvp, int* __restrict__ topip)
{
  __shared__ float4 qs[256][2];
  __shared__ float csch[8 * 512];
  const int tid = threadIdx.x;
  const int split = blockIdx.x & 7;          // consecutive blocks -> different XCDs -> same split per XCD
  const int m0 = (blockIdx.x >> 3) * 8;
  {
    int k = tid;
    float4 v0, v1;
    v0.x = qh[(size_t)(m0 + 0) * 256 + k]; v0.y = qh[(size_t)(m0 + 1) * 256 + k];
    v0.z = qh[(size_t)(m0 + 2) * 256 + k]; v0.w = qh[(size_t)(m0 + 3) * 256 + k];
    v1.x = qh[(size_t)(m0 + 4) * 256 + k]; v1.y = qh[(size_t)(m0 + 5) * 256 + k];
    v1.z = qh[(size_t)(m0 + 6) * 256 + k]; v1.w = qh[(size_t)(m0 + 7) * 256 + k];
    qs[k][0] = v0; qs[k][1] = v1;
  }
  __syncthreads();
  const int lane = tid & 63;
  const int wv = tid >> 6;

  float tv0[10], tv1[10];
  int   tj0[10], tj1[10];
  int   tn0 = 0, tn1 = 0;
  float tmv0 = -INFINITY, tmv1 = -INFINITY;
  int   tmi0 = 0, tmi1 = 0;

  auto process_row = [&](int r, float (&tv)[10], int (&tj)[10], int& tn,
                         float& tmv, int& tmi, int jb) {
    float4 c0 = *(const float4*)&csch[r * 512 + lane * 8];
    float4 c1 = *(const float4*)&csch[r * 512 + lane * 8 + 4];
    float cv[8] = {c0.x, c0.y, c0.z, c0.w, c1.x, c1.y, c1.z, c1.w};
    const int cj0 = jb + lane * 8;
    while (true) {
      float bv = -INFINITY; int bj = 0x7fffffff;
#pragma unroll
      for (int u = 0; u < 8; ++u) {
        if (cv[u] > bv) { bv = cv[u]; bj = cj0 + u; }
      }
#pragma unroll
      for (int o = 32; o; o >>= 1) {
        float ov = __shfl_down(bv, o, 64);
        int   oj = __shfl_down(bj, o, 64);
        if (ov > bv || (ov == bv && oj < bj)) { bv = ov; bj = oj; }
      }
      bv = __shfl(bv, 0, 64); bj = __shfl(bj, 0, 64);
      bool take;
      if (tn < 10) take = true;
      else take = (bv > tmv) || (bv == tmv && bj < tmi);
      if (!take) break;
      if (tn < 10) {
#pragma unroll
        for (int s = 0; s < 10; ++s) if (s == tn) { tv[s] = bv; tj[s] = bj; }
        tn++;
        if (tn == 10) {
          float mv = tv[0]; int mi = tj[0];
#pragma unroll
          for (int s = 1; s < 10; ++s) {
            bool w = (tv[s] < mv) || (tv[s] == mv && tj[s] > mi);
            if (w) { mv = tv[s]; mi = tj[s]; }
          }
          tmv = mv; tmi = mi;
        }
      } else {
        int ms = 0; float mv = tv[0]; int mi = tj[0];
#pragma unroll
        for (int s = 1; s < 10; ++s) {
          bool w = (tv[s] < mv) || (tv[s] == mv && tj[s] > mi);
          if (w) { ms = s; mv = tv[s]; mi = tj[s]; }
        }
#pragma unroll
        for (int s = 0; s < 10; ++s) if (s == ms) { tv[s] = bv; tj[s] = bj; }
        mv = tv[0]; mi = tj[0];
#pragma unroll
        for (int s = 1; s < 10; ++s) {
          bool w = (tv[s] < mv) || (tv[s] == mv && tj[s] > mi);
          if (w) { mv = tv[s]; mi = tj[s]; }
        }
        tmv = mv; tmi = mi;
      }
#pragma unroll
      for (int u = 0; u < 8; ++u) if (cj0 + u == bj) cv[u] = -INFINITY;
    }
  };

  for (int ci = 0; ci < 5; ++ci) {
    const int ch = split * 5 + ci;
    const int jb = ch * 512;
    float acc[8][2];
#pragma unroll
    for (int r = 0; r < 8; ++r) { acc[r][0] = 0.f; acc[r][1] = 0.f; }
    const float* kp = khT + jb + tid;

    float b0c[4], b1c[4], b0n[4], b1n[4];
#pragma unroll
    for (int kk = 0; kk < 4; ++kk) {
      b0c[kk] = kp[(size_t)kk * NSAMP];
      b1c[kk] = kp[(size_t)kk * NSAMP + 256];
    }
    for (int k4 = 0; k4 < 64; ++k4) {
      int nk4 = (k4 + 1) & 63;
      const float* pn = kp + (size_t)nk4 * 4 * NSAMP;
#pragma unroll
      for (int kk = 0; kk < 4; ++kk) {
        b0n[kk] = pn[(size_t)kk * NSAMP];
        b1n[kk] = pn[(size_t)kk * NSAMP + 256];
      }
#pragma unroll
      for (int kk = 0; kk < 4; ++kk) {
        float4 qa = qs[k4 * 4 + kk][0];
        float4 qb = qs[k4 * 4 + kk][1];
        float b0 = b0c[kk], b1 = b1c[kk];
        acc[0][0] += qa.x * b0; acc[1][0] += qa.y * b0; acc[2][0] += qa.z * b0; acc[3][0] += qa.w * b0;
        acc[4][0] += qb.x * b0; acc[5][0] += qb.y * b0; acc[6][0] += qb.z * b0; acc[7][0] += qb.w * b0;
        acc[0][1] += qa.x * b1; acc[1][1] += qa.y * b1; acc[2][1] += qa.z * b1; acc[3][1] += qa.w * b1;
        acc[4][1] += qb.x * b1; acc[5][1] += qb.y * b1; acc[6][1] += qb.z * b1; acc[7][1] += qb.w * b1;
      }
#pragma unroll
      for (int q = 0; q < 4; ++q) { b0c[q] = b0n[q]; b1c[q] = b1n[q]; }
    }
    __syncthreads();
#pragma unroll
    for (int r = 0; r < 8; ++r) {
      csch[r * 512 + tid] = acc[r][0];
      csch[r * 512 + 256 + tid] = acc[r][1];
    }
    __syncthreads();
    process_row(wv,     tv0, tj0, tn0, tmv0, tmi0, jb);
    process_row(wv + 4, tv1, tj1, tn1, tmv1, tmi1, jb);
  }
  __syncthreads();

  if (lane == 0) {
    int row0 = m0 + wv;
#pragma unroll
    for (int s = 0; s < 10; ++s) {
      topvp[(size_t)row0 * 80 + split * 10 + s] = tv0[s];
      topip[(size_t)row0 * 80 + split * 10 + s] = tj0[s];
    }
    int row1 = m0 + wv + 4;
#pragma unroll
    for (int s = 0; s < 10; ++s) {
      topvp[(size_t)row1 * 80 + split * 10 + s] = tv1[s];
      topip[(size_t)row1 * 80 + split * 10 + s] = tj1[s];
    }
  }
}

// merge 8 splits x 10 candidates -> global top-10 per row (value desc, idx asc)
__global__ void merge_topk(const float* __restrict__ topvp, const int* __restrict__ topip,
                           float* __restrict__ topv, int* __restrict__ topi)
{
  const int wv = threadIdx.x >> 6;
  const int lane = threadIdx.x & 63;
  const int row = blockIdx.x * 4 + wv;
  float v0 = topvp[(size_t)row * 80 + lane];
  int   i0 = topip[(size_t)row * 80 + lane];
  float v1 = (lane < 16) ? topvp[(size_t)row * 80 + 64 + lane] : -INFINITY;
  int   i1 = (lane < 16) ? topip[(size_t)row * 80 + 64 + lane] : 0x7fffffff;
  for (int s = 0; s < 10; ++s) {
    float bv = v0; int bj = i0;
    if (v1 > bv || (v1 == bv && i1 < bj)) { bv = v1; bj = i1; }
#pragma unroll
    for (int o = 1; o < 64; o <<= 1) {
      float ov = __shfl_xor(bv, o, 64);
      int   oj = __shfl_xor(bj, o, 64);
      if (ov > bv || (ov == bv && oj < bj)) { bv = ov; bj = oj; }
    }
    if (lane == 0) { topv[row * 10 + s] = bv; topi[row * 10 + s] = bj; }
    if (i0 == bj) { v0 = -INFINITY; i0 = 0x7fffffff; }
    if (i1 == bj) { v1 = -INFINITY; i1 = 0x7fffffff; }
  }
}

// ---------------------------------------------------------------- final: agg + fc
__global__ void final_kernel(const float* __restrict__ mb, const float* __restrict__ kh,
                             const float* __restrict__ topv, const int* __restrict__ topi,
                             const float* __restrict__ fcW, const float* __restrict__ fcb,
                             float* __restrict__ y)
{
  __shared__ float red[256];
  int n = blockIdx.x, c = threadIdx.x;
  float agg = 0.f;
#pragma unroll
  for (int k = 0; k < 10; ++k) {
    float w = topv[n * 10 + k] / 10.0f;
    int idx = topi[n * 10 + k];
    agg += w * kh[(size_t)idx * 256 + c];
  }
  float val = fcW[c] * mb[(size_t)n * 256 + c] + fcW[256 + c] * agg;
  red[c] = val;
  __syncthreads();
  for (int o = 128; o; o >>= 1) { if (c < o) red[c] += red[c + o]; __syncthreads(); }
  if (c == 0) y[n] = red[0] + fcb[0];
}

// ---------------------------------------------------------------- launch
extern "C" void kernel_launch(void* const* d_in, const int* in_sizes, int n_in,
                              void* d_out, int out_size, void* d_ws, size_t ws_size,
                              hipStream_t stream)
{
  const float* inp    = (const float*)d_in[0];
  const float* trainh = (const float*)d_in[1];
  const float* thd    = (const float*)d_in[2];
  const float* Wih0   = (const float*)d_in[3];
  const float* Whh0   = (const float*)d_in[4];
  const float* bih0   = (const float*)d_in[5];
  const float* bhh0   = (const float*)d_in[6];
  const float* Wih1   = (const float*)d_in[7];
  const float* Whh1   = (const float*)d_in[8];
  const float* bih1   = (const float*)d_in[9];
  const float* bhh1   = (const float*)d_in[10];
  const float* lin0W  = (const float*)d_in[11];
  const float* lin0b  = (const float*)d_in[12];
  const float* lin1W  = (const float*)d_in[13];
  const float* lin1b  = (const float*)d_in[14];
  const float* lin2W  = (const float*)d_in[15];
  const float* lin2b  = (const float*)d_in[16];
  const float* p1W    = (const float*)d_in[17];
  const float* p2W    = (const float*)d_in[18];
  const float* fcW    = (const float*)d_in[19];
  const float* fcb    = (const float*)d_in[20];

  float* ws = (float*)d_ws;
  float* P0     = ws + 0;          // 256x256x3 = 196608
  float* P1     = ws + 196608;     // 512x256x3 = 393216
  float* WT_l0  = ws + 589824;     // 256x512
  float* WT_l1  = ws + 720896;     // 512x512
  float* WT_l2  = ws + 983040;     // 512x256
  float* WT_p1  = ws + 1114112;    // 256x256
  float* WT_p2  = ws + 1179648;    // 256x256
  float* h0a    = ws + 1245184;    // hT buffers [256][2048]
  float* h0b    = ws + 1769472;
  float* h1a    = ws + 2293760;
  float* h1b    = ws + 2818048;
  float* mb1    = ws + 3342336;    // 2048x512 (reused for topk candidates)
  float* mb2    = ws + 4390912;    // 2048x512 (reused for mbday partials)
  float* mbf    = ws + 5439488;    // 2048x256
  float* mbday  = ws + 5963776;    // 4x256
  float* qbuf   = ws + 5964800;    // 2048x256
  float* kh     = ws + 6489088;    // 20480x256
  float* khT    = ws + 11731968;   // 256x20480 (normalized)
  float* khn    = ws + 16974848;   // 20480
  float* qn     = ws + 16995328;   // 2048
  float* topv   = ws + 16997376;   // 2048x10
  int*   dayidx = (int*)(ws + 17017856);
  int*   rowsrc = (int*)(ws + 17017920);
  int*   topi   = (int*)(ws + 17038400);
  float* topvp  = mb1;                       // 2048x80
  int*   topip  = (int*)(mb1 + 163840);      // 2048x80
  float* mbpart = mb2;                       // 4x8x256

  PrepArgs pa;
  pa.src[0] = lin0W; pa.dst[0] = WT_l0;  pa.N[0] = 512; pa.K[0] = 256;
  pa.src[1] = lin1W; pa.dst[1] = WT_l1;  pa.N[1] = 512; pa.K[1] = 512;
  pa.src[2] = lin2W; pa.dst[2] = WT_l2;  pa.N[2] = 256; pa.K[2] = 512;
  pa.src[3] = p1W;   pa.dst[3] = WT_p1;  pa.N[3] = 256; pa.K[3] = 256;
  pa.src[4] = p2W;   pa.dst[4] = WT_p2;  pa.N[4] = 256; pa.K[4] = 256;
  prep_weights<<<dim3(64, 5), dim3(256), 0, stream>>>(pa);
  prep_packed<<<1536, 256, 0, stream>>>(Whh0, Wih1, Whh1, P0, P1);

  hipMemsetAsync(h0a, 0, (size_t)NROW * HID * 4, stream);
  hipMemsetAsync(h1a, 0, (size_t)NROW * HID * 4, stream);

  float *h0c = h0a, *h0n = h0b, *h1c = h1a, *h1n = h1b;
  for (int t = 0; t < T_SEQ; ++t) {
    gru0_step<<<dim3(8, 64), dim3(32, 8), 0, stream>>>(h0c, h0n, inp, P0, Wih0, bih0, bhh0, t);
    gru1_step<<<dim3(8, 64), dim3(32, 8), 0, stream>>>(h0n, h1c, h1n, P1, bih1, bhh1);
    float* tmp;
    tmp = h0c; h0c = h0n; h0n = tmp;
    tmp = h1c; h1c = h1n; h1n = tmp;
  }
  // h1c holds final h1 (transposed). Transpose to row-major into h0b (dead).
  float* hrow = h0b;
  transpose_kT<<<dim3(64, 8), 256, 0, stream>>>(h1c, hrow);

  gemm_act<<<dim3(16, 64), dim3(32, 8), 0, stream>>>(hrow, nullptr, WT_l0, lin0b, mb1, 2048, 512, 256, 1);
  gemm_act<<<dim3(16, 64), dim3(32, 8), 0, stream>>>(mb1, nullptr, WT_l1, lin1b, mb2, 2048, 512, 512, 1);
  gemm_act<<<dim3(8, 64),  dim3(32, 8), 0, stream>>>(mb2, nullptr, WT_l2, lin2b, mbf, 2048, 256, 512, 1);

  mbday_part<<<dim3(4, 8), 256, 0, stream>>>(mbf, mbpart);
  mbday_fin<<<4, 256, 0, stream>>>(mbpart, mbday);
  daytopk_kernel<<<4, 256, 0, stream>>>(mbday, thd, dayidx);
  rowsrc_kernel<<<80, 256, 0, stream>>>(dayidx, rowsrc);

  gemm_act<<<dim3(8, 640), dim3(32, 8), 0, stream>>>(trainh, rowsrc, WT_p2, nullptr, kh, 20480, 256, 256, 0);
  gemm_act<<<dim3(8, 64),  dim3(32, 8), 0, stream>>>(mbf, nullptr, WT_p1, nullptr, qbuf, 2048, 256, 256, 0);

  rownorm_kernel<<<5120, 256, 0, stream>>>(kh, khn, 20480);
  rownorm_kernel<<<512, 256, 0, stream>>>(qbuf, qn, 2048);
  qnorm_kernel<<<2048, 256, 0, stream>>>(qbuf, qn);
  khT_kernel<<<dim3(640, 8), 256, 0, stream>>>(kh, khn, khT);

  csmax_kernel<<<2048, 256, 0, stream>>>(qbuf, khT, topvp, topip);
  merge_topk<<<512, 256, 0, stream>>>(topvp, topip, topv, topi);
  final_kernel<<<2048, 256, 0, stream>>>(mbf, kh, topv, topi, fcW, fcb, (float*)d_out);

  (void)in_sizes; (void)n_in; (void)out_size; (void)ws_size;
}

// Round 4
// 4696.362 us; speedup vs baseline: 1.9434x; 1.9434x over previous
//
#include <hip/hip_runtime.h>
#include <cmath>
#include <cstdint>

#define D_FEAT 6
#define T_SEQ  60
#define HID    256
#define G3     768
#define NROW   2048
#define NSAMP  20480

__device__ __forceinline__ float sigmoidf_(float x) { return 1.0f / (1.0f + expf(-x)); }

// ---------------------------------------------------------------- weight prep
struct PrepArgs {
  const float* src[8];
  float* dst[8];
  int N[8], K[8], ro[8];
};

__global__ void prep_weights(PrepArgs a) {
  int seg = blockIdx.y;
  const float* S = a.src[seg];
  float* D = a.dst[seg];
  int N = a.N[seg], K = a.K[seg], ro = a.ro[seg];
  int total = N * K;
  for (int i = blockIdx.x * blockDim.x + threadIdx.x; i < total; i += gridDim.x * blockDim.x) {
    int n = i / K, k = i - n * K;
    D[(size_t)(k + ro) * N + n] = S[i];   // WT[k][n] = W[n][k]
  }
}

// ---------------------------------------------------------------- persistent fused GRU
// Grid: 256 blocks x 256 threads. Block owns 8 stocks, runs all 60 steps in LDS.
// Thread layout: wave w = tid>>6: rg = w>>1 (rows rg*4..+3), oh = w&1.
// Thread accumulates 6 gate-outputs o_u = oh*384 + u*64 + lane, for 4 rows.
// Gate sums exchanged via LDS (gA/gB, pitch 9 = conflict-free); combine: j = tid.
__device__ __forceinline__ void phase_acc(const float* __restrict__ A,   // LDS [k*8 + row]
                                          const float* __restrict__ B,   // global [k*768 + o]
                                          int rg, int obase, float (&acc)[6][4])
{
  const float* pB = B + obase;
  float4 a0 = *(const float4*)(A + rg * 4);
  float4 a1;
  float b0[6], b1[6];
#pragma unroll
  for (int u = 0; u < 6; ++u) b0[u] = pB[u * 64];
  for (int k = 0; k < 256; k += 2) {
    const float* p1 = pB + (size_t)(k + 1) * 768;
    a1 = *(const float4*)(A + (k + 1) * 8 + rg * 4);
#pragma unroll
    for (int u = 0; u < 6; ++u) b1[u] = p1[u * 64];
#pragma unroll
    for (int u = 0; u < 6; ++u) {
      acc[u][0] += a0.x * b0[u];
      acc[u][1] += a0.y * b0[u];
      acc[u][2] += a0.z * b0[u];
      acc[u][3] += a0.w * b0[u];
    }
    int k2 = (k + 2) & 255;           // wrap: last prefetch unused
    const float* p2 = pB + (size_t)k2 * 768;
    a0 = *(const float4*)(A + k2 * 8 + rg * 4);
#pragma unroll
    for (int u = 0; u < 6; ++u) b0[u] = p2[u * 64];
#pragma unroll
    for (int u = 0; u < 6; ++u) {
      acc[u][0] += a1.x * b1[u];
      acc[u][1] += a1.y * b1[u];
      acc[u][2] += a1.z * b1[u];
      acc[u][3] += a1.w * b1[u];
    }
  }
}

__global__ __launch_bounds__(256, 1)
void gru_fused(const float* __restrict__ inp, const float* __restrict__ WThh0,
               const float* __restrict__ WTcat, const float* __restrict__ Wih0,
               const float* __restrict__ bih0, const float* __restrict__ bhh0,
               const float* __restrict__ bih1, const float* __restrict__ bhh1,
               float* __restrict__ hrow)
{
  __shared__ float h0T[2048];     // [j*8 + row]
  __shared__ float h1T[2048];
  __shared__ float xls[2880];     // [(i*60+t)*8 + row]
  __shared__ float gA[6912];      // [o*9 + row], o<768
  __shared__ float gB[2304];      // [(o-512)*9 + row]

  const int tid = threadIdx.x;
  const int lane = tid & 63;
  const int w = tid >> 6;
  const int rg = w >> 1;
  const int oh = w & 1;
  const int obase = oh * 384 + lane;
  const int m0 = blockIdx.x * 8;

  // stage x (transposed) and zero h tiles
  for (int c = tid; c < 2880; c += 256) {
    int row = c / 360, it = c - row * 360;
    xls[it * 8 + row] = inp[(size_t)(m0 + row) * 360 + it];
  }
  for (int c = tid; c < 2048; c += 256) { h0T[c] = 0.f; h1T[c] = 0.f; }

  float h0col[8], h1col[8];
#pragma unroll
  for (int r = 0; r < 8; ++r) { h0col[r] = 0.f; h1col[r] = 0.f; }

  // per-o biases (accumulator role)
  float bi0u[6], bh0u[6], bi1u[6], bh1u[6];
  int ou[6];
#pragma unroll
  for (int u = 0; u < 6; ++u) {
    int o = obase + u * 64;
    ou[u] = o;
    bi0u[u] = bih0[o]; bh0u[u] = bhh0[o];
    bi1u[u] = bih1[o]; bh1u[u] = bhh1[o];
  }
  __syncthreads();

  for (int t = 0; t < T_SEQ; ++t) {
    // ================= layer 0 =================
    float acc1[6][4], acc2[6][4];
#pragma unroll
    for (int u = 0; u < 6; ++u)
#pragma unroll
      for (int r = 0; r < 4; ++r) { acc1[u][r] = bi0u[u]; acc2[u][r] = 0.f; }
    // x-part (K=6): acc1 = bih + sum_i x*Wih0  (matches ref add order)
#pragma unroll
    for (int i = 0; i < 6; ++i) {
      float4 a = *(const float4*)&xls[(i * 60 + t) * 8 + rg * 4];
#pragma unroll
      for (int u = 0; u < 6; ++u) {
        float b = Wih0[(size_t)ou[u] * 6 + i];
        acc1[u][0] += a.x * b; acc1[u][1] += a.y * b;
        acc1[u][2] += a.z * b; acc1[u][3] += a.w * b;
      }
    }
    // h-part (K=256)
    phase_acc(h0T, WThh0, rg, obase, acc2);
    // write gate sums: r/z: xw + (gh+bhh); n: gA=xw, gB=gh+bhh
#pragma unroll
    for (int u = 0; u < 6; ++u) {
      int o = ou[u];
      if (o < 512) {
#pragma unroll
        for (int r = 0; r < 4; ++r)
          gA[o * 9 + rg * 4 + r] = acc1[u][r] + (acc2[u][r] + bh0u[u]);
      } else {
#pragma unroll
        for (int r = 0; r < 4; ++r) {
          gA[o * 9 + rg * 4 + r] = acc1[u][r];
          gB[(o - 512) * 9 + rg * 4 + r] = acc2[u][r] + bh0u[u];
        }
      }
    }
    __syncthreads();
    // combine (j = tid): update h0col, rewrite h0T
    {
      float hn[8];
#pragma unroll
      for (int r = 0; r < 8; ++r) {
        float pr = gA[tid * 9 + r];
        float pz = gA[(256 + tid) * 9 + r];
        float xn = gA[(512 + tid) * 9 + r];
        float hh = gB[tid * 9 + r];
        float rr = sigmoidf_(pr);
        float zz = sigmoidf_(pz);
        float nn = tanhf(xn + rr * hh);
        h0col[r] = (1.f - zz) * nn + zz * h0col[r];
        hn[r] = h0col[r];
      }
      *(float4*)&h0T[tid * 8] = *(float4*)&hn[0];
      *(float4*)&h0T[tid * 8 + 4] = *(float4*)&hn[4];
    }
    __syncthreads();
    // ================= layer 1 =================
    // phase 1: x = h0 (K=256) into acc1 (init 0)
#pragma unroll
    for (int u = 0; u < 6; ++u)
#pragma unroll
      for (int r = 0; r < 4; ++r) acc1[u][r] = 0.f;
    phase_acc(h0T, WTcat, rg, obase, acc1);
    // phase 2: h-part (K=256). r/z continue acc1 (continuous sum, matches ref);
    // n keeps separate.
#pragma unroll
    for (int u = 0; u < 6; ++u) {
      bool rz = (ou[u] < 512);
#pragma unroll
      for (int r = 0; r < 4; ++r) acc2[u][r] = rz ? acc1[u][r] : 0.f;
    }
    phase_acc(h1T, WTcat + (size_t)256 * 768, rg, obase, acc2);
#pragma unroll
    for (int u = 0; u < 6; ++u) {
      int o = ou[u];
      if (o < 512) {
#pragma unroll
        for (int r = 0; r < 4; ++r)
          gA[o * 9 + rg * 4 + r] = (acc2[u][r] + bi1u[u]) + bh1u[u];
      } else {
#pragma unroll
        for (int r = 0; r < 4; ++r) {
          gA[o * 9 + rg * 4 + r] = acc1[u][r] + bi1u[u];
          gB[(o - 512) * 9 + rg * 4 + r] = acc2[u][r] + bh1u[u];
        }
      }
    }
    __syncthreads();
    // combine layer 1
    {
      float hn[8];
#pragma unroll
      for (int r = 0; r < 8; ++r) {
        float pr = gA[tid * 9 + r];
        float pz = gA[(256 + tid) * 9 + r];
        float xn = gA[(512 + tid) * 9 + r];
        float hh = gB[tid * 9 + r];
        float rr = sigmoidf_(pr);
        float zz = sigmoidf_(pz);
        float nn = tanhf(xn + rr * hh);
        h1col[r] = (1.f - zz) * nn + zz * h1col[r];
        hn[r] = h1col[r];
      }
      *(float4*)&h1T[tid * 8] = *(float4*)&hn[0];
      *(float4*)&h1T[tid * 8 + 4] = *(float4*)&hn[4];
    }
    __syncthreads();
  }

  // write final h1 row-major
#pragma unroll
  for (int r = 0; r < 8; ++r)
    hrow[(size_t)(m0 + r) * 256 + tid] = h1col[r];
}

// ---------------------------------------------------------------- generic GEMM
__global__ __launch_bounds__(256, 2)
void gemm_act(const float* __restrict__ A, const int* __restrict__ rowsrc,
              const float* __restrict__ WT, const float* __restrict__ bias,
              float* __restrict__ C, int M, int N, int K, int act)
{
  __shared__ float4 As4[128 * 32];
  const int tx = threadIdx.x, ty = threadIdx.y;
  const int tid = ty * 32 + tx;
  const int n0 = blockIdx.x * 32, m0 = blockIdx.y * 32;
  const int K4 = K >> 2;

  for (int c = tid; c < K4 * 32; c += 256) {
    int k4 = c % K4, m = c / K4;
    int row = m0 + m;
    if (rowsrc) row = rowsrc[row];
    As4[k4 * 32 + m] = *(const float4*)(A + (size_t)row * K + k4 * 4);
  }
  __syncthreads();

  float acc[4] = {0,0,0,0};
  const int n = n0 + tx;
  const float* pb = WT + n;

  float bc[4], bn_[4];
#pragma unroll
  for (int kk = 0; kk < 4; ++kk) bc[kk] = pb[(size_t)kk * N];
  for (int k4 = 0; k4 < K4; ++k4) {
    int nk4 = (k4 + 1 < K4) ? (k4 + 1) : 0;
    const float* pn = pb + (size_t)nk4 * 4 * N;
#pragma unroll
    for (int kk = 0; kk < 4; ++kk) bn_[kk] = pn[(size_t)kk * N];
    float4 a0 = As4[k4 * 32 + ty * 4 + 0];
    float4 a1 = As4[k4 * 32 + ty * 4 + 1];
    float4 a2 = As4[k4 * 32 + ty * 4 + 2];
    float4 a3 = As4[k4 * 32 + ty * 4 + 3];
#pragma unroll
    for (int kk = 0; kk < 4; ++kk) {
      float b = bc[kk];
      acc[0] += ((const float*)&a0)[kk] * b;
      acc[1] += ((const float*)&a1)[kk] * b;
      acc[2] += ((const float*)&a2)[kk] * b;
      acc[3] += ((const float*)&a3)[kk] * b;
    }
#pragma unroll
    for (int q = 0; q < 4; ++q) bc[q] = bn_[q];
  }
  float bb = bias ? bias[n] : 0.f;
#pragma unroll
  for (int r = 0; r < 4; ++r) {
    float v = acc[r] + bb;
    if (act) v = (v >= 0.f) ? v : 0.01f * v;
    C[(size_t)(m0 + ty * 4 + r) * N + n] = v;
  }
}

// ---------------------------------------------------------------- small stages
__global__ void mbday_part(const float* __restrict__ mbf, float* __restrict__ part) {
  int d = blockIdx.x, sl = blockIdx.y, c = threadIdx.x;
  float s = 0.f;
  int base = d * 512 + sl * 64;
  for (int st = 0; st < 64; ++st) s += mbf[(size_t)(base + st) * 256 + c];
  part[(size_t)(d * 8 + sl) * 256 + c] = s;
}

__global__ void mbday_fin(const float* __restrict__ part, float* __restrict__ mbday) {
  int d = blockIdx.x, c = threadIdx.x;
  float s = 0.f;
#pragma unroll
  for (int p = 0; p < 8; ++p) s += part[(size_t)(d * 8 + p) * 256 + c];
  mbday[d * 256 + c] = s * (1.0f / 512.0f);
}

__global__ void daytopk_kernel(const float* __restrict__ mbday, const float* __restrict__ thd,
                               int* __restrict__ dayidx) {
  __shared__ float mbs[256];
  __shared__ float sim[256];
  __shared__ float red[256];
  __shared__ int   redi[256];
  const int d = blockIdx.x, t = threadIdx.x;
  mbs[t] = mbday[d * 256 + t];
  __syncthreads();
  red[t] = mbs[t] * mbs[t];
  __syncthreads();
  for (int o = 128; o; o >>= 1) { if (t < o) red[t] += red[t + o]; __syncthreads(); }
  float xn = sqrtf(red[0]);
  float v = -INFINITY;
  if (t < 240) {
    float dot = 0.f, yn2 = 0.f;
    for (int k = 0; k < 256; ++k) {
      float y = thd[t * 256 + k];
      dot += mbs[k] * y;
      yn2 += y * y;
    }
    float den = xn * sqrtf(yn2);
    v = (den > 0.f) ? dot / den : 0.f;
  }
  sim[t] = v;
  __syncthreads();
  for (int it = 0; it < 10; ++it) {
    red[t] = sim[t]; redi[t] = t;
    __syncthreads();
    for (int o = 128; o; o >>= 1) {
      if (t < o) {
        if (red[t + o] > red[t] || (red[t + o] == red[t] && redi[t + o] < redi[t])) {
          red[t] = red[t + o]; redi[t] = redi[t + o];
        }
      }
      __syncthreads();
    }
    if (t == 0) { int bi = redi[0]; dayidx[d * 10 + it] = bi; sim[bi] = -INFINITY; }
    __syncthreads();
  }
}

__global__ void rowsrc_kernel(const int* __restrict__ dayidx, int* __restrict__ rowsrc) {
  int r = blockIdx.x * 256 + threadIdx.x;
  if (r < NSAMP) rowsrc[r] = dayidx[r >> 9] * 512 + (r & 511);
}

__global__ void rownorm_kernel(const float* __restrict__ X, float* __restrict__ out, int rows) {
  int w = threadIdx.x >> 6;
  int lane = threadIdx.x & 63;
  int row = blockIdx.x * 4 + w;
  if (row >= rows) return;
  float4 x = *(const float4*)(X + (size_t)row * 256 + lane * 4);
  float s = x.x * x.x + x.y * x.y + x.z * x.z + x.w * x.w;
#pragma unroll
  for (int o = 32; o; o >>= 1) s += __shfl_down(s, o, 64);
  if (lane == 0) out[row] = sqrtf(s);
}

__global__ void qnorm_kernel(float* __restrict__ q, const float* __restrict__ qn) {
  int i = blockIdx.x * 256 + threadIdx.x;
  int row = i >> 8;
  float n = qn[row];
  q[i] = (n > 0.f) ? q[i] / n : 0.f;
}

__global__ void khT_kernel(const float* __restrict__ kh, const float* __restrict__ khn,
                           float* __restrict__ khT) {
  __shared__ float tile[32][33];
  int jb = blockIdx.x * 32;
  int kb = blockIdx.y * 32;
  int tx = threadIdx.x & 31, tyy = threadIdx.x >> 5;
  for (int rr = tyy; rr < 32; rr += 8) {
    float n = khn[jb + rr];
    float v = kh[(size_t)(jb + rr) * 256 + kb + tx];
    tile[rr][tx] = (n > 0.f) ? v / n : 0.f;
  }
  __syncthreads();
  for (int rr = tyy; rr < 32; rr += 8) {
    khT[(size_t)(kb + rr) * NSAMP + jb + tx] = tile[tx][rr];
  }
}

// ---------------------------------------------------------------- cs GEMM + top-10 (split, XCD-swizzled)
__global__ __launch_bounds__(256, 4)
void csmax_kernel(const float* __restrict__ qh, const float* __restrict__ khT,
                  float* __restrict__ topvp, int* __restrict__ topip)
{
  __shared__ float4 qs[256][2];
  __shared__ float csch[8 * 512];
  const int tid = threadIdx.x;
  const int split = blockIdx.x & 7;
  const int m0 = (blockIdx.x >> 3) * 8;
  {
    int k = tid;
    float4 v0, v1;
    v0.x = qh[(size_t)(m0 + 0) * 256 + k]; v0.y = qh[(size_t)(m0 + 1) * 256 + k];
    v0.z = qh[(size_t)(m0 + 2) * 256 + k]; v0.w = qh[(size_t)(m0 + 3) * 256 + k];
    v1.x = qh[(size_t)(m0 + 4) * 256 + k]; v1.y = qh[(size_t)(m0 + 5) * 256 + k];
    v1.z = qh[(size_t)(m0 + 6) * 256 + k]; v1.w = qh[(size_t)(m0 + 7) * 256 + k];
    qs[k][0] = v0; qs[k][1] = v1;
  }
  __syncthreads();
  const int lane = tid & 63;
  const int wv = tid >> 6;

  float tv0[10], tv1[10];
  int   tj0[10], tj1[10];
  int   tn0 = 0, tn1 = 0;
  float tmv0 = -INFINITY, tmv1 = -INFINITY;
  int   tmi0 = 0, tmi1 = 0;

  auto process_row = [&](int r, float (&tv)[10], int (&tj)[10], int& tn,
                         float& tmv, int& tmi, int jb) {
    float4 c0 = *(const float4*)&csch[r * 512 + lane * 8];
    float4 c1 = *(const float4*)&csch[r * 512 + lane * 8 + 4];
    float cv[8] = {c0.x, c0.y, c0.z, c0.w, c1.x, c1.y, c1.z, c1.w};
    const int cj0 = jb + lane * 8;
    while (true) {
      float bv = -INFINITY; int bj = 0x7fffffff;
#pragma unroll
      for (int u = 0; u < 8; ++u) {
        if (cv[u] > bv) { bv = cv[u]; bj = cj0 + u; }
      }
#pragma unroll
      for (int o = 32; o; o >>= 1) {
        float ov = __shfl_down(bv, o, 64);
        int   oj = __shfl_down(bj, o, 64);
        if (ov > bv || (ov == bv && oj < bj)) { bv = ov; bj = oj; }
      }
      bv = __shfl(bv, 0, 64); bj = __shfl(bj, 0, 64);
      bool take;
      if (tn < 10) take = true;
      else take = (bv > tmv) || (bv == tmv && bj < tmi);
      if (!take) break;
      if (tn < 10) {
#pragma unroll
        for (int s = 0; s < 10; ++s) if (s == tn) { tv[s] = bv; tj[s] = bj; }
        tn++;
        if (tn == 10) {
          float mv = tv[0]; int mi = tj[0];
#pragma unroll
          for (int s = 1; s < 10; ++s) {
            bool w = (tv[s] < mv) || (tv[s] == mv && tj[s] > mi);
            if (w) { mv = tv[s]; mi = tj[s]; }
          }
          tmv = mv; tmi = mi;
        }
      } else {
        int ms = 0; float mv = tv[0]; int mi = tj[0];
#pragma unroll
        for (int s = 1; s < 10; ++s) {
          bool w = (tv[s] < mv) || (tv[s] == mv && tj[s] > mi);
          if (w) { ms = s; mv = tv[s]; mi = tj[s]; }
        }
#pragma unroll
        for (int s = 0; s < 10; ++s) if (s == ms) { tv[s] = bv; tj[s] = bj; }
        mv = tv[0]; mi = tj[0];
#pragma unroll
        for (int s = 1; s < 10; ++s) {
          bool w = (tv[s] < mv) || (tv[s] == mv && tj[s] > mi);
          if (w) { mv = tv[s]; mi = tj[s]; }
        }
        tmv = mv; tmi = mi;
      }
#pragma unroll
      for (int u = 0; u < 8; ++u) if (cj0 + u == bj) cv[u] = -INFINITY;
    }
  };

  for (int ci = 0; ci < 5; ++ci) {
    const int ch = split * 5 + ci;
    const int jb = ch * 512;
    float acc[8][2];
#pragma unroll
    for (int r = 0; r < 8; ++r) { acc[r][0] = 0.f; acc[r][1] = 0.f; }
    const float* kp = khT + jb + tid;

    float b0c[4], b1c[4], b0n[4], b1n[4];
#pragma unroll
    for (int kk = 0; kk < 4; ++kk) {
      b0c[kk] = kp[(size_t)kk * NSAMP];
      b1c[kk] = kp[(size_t)kk * NSAMP + 256];
    }
    for (int k4 = 0; k4 < 64; ++k4) {
      int nk4 = (k4 + 1) & 63;
      const float* pn = kp + (size_t)nk4 * 4 * NSAMP;
#pragma unroll
      for (int kk = 0; kk < 4; ++kk) {
        b0n[kk] = pn[(size_t)kk * NSAMP];
        b1n[kk] = pn[(size_t)kk * NSAMP + 256];
      }
#pragma unroll
      for (int kk = 0; kk < 4; ++kk) {
        float4 qa = qs[k4 * 4 + kk][0];
        float4 qb = qs[k4 * 4 + kk][1];
        float b0 = b0c[kk], b1 = b1c[kk];
        acc[0][0] += qa.x * b0; acc[1][0] += qa.y * b0; acc[2][0] += qa.z * b0; acc[3][0] += qa.w * b0;
        acc[4][0] += qb.x * b0; acc[5][0] += qb.y * b0; acc[6][0] += qb.z * b0; acc[7][0] += qb.w * b0;
        acc[0][1] += qa.x * b1; acc[1][1] += qa.y * b1; acc[2][1] += qa.z * b1; acc[3][1] += qa.w * b1;
        acc[4][1] += qb.x * b1; acc[5][1] += qb.y * b1; acc[6][1] += qb.z * b1; acc[7][1] += qb.w * b1;
      }
#pragma unroll
      for (int q = 0; q < 4; ++q) { b0c[q] = b0n[q]; b1c[q] = b1n[q]; }
    }
    __syncthreads();
#pragma unroll
    for (int r = 0; r < 8; ++r) {
      csch[r * 512 + tid] = acc[r][0];
      csch[r * 512 + 256 + tid] = acc[r][1];
    }
    __syncthreads();
    process_row(wv,     tv0, tj0, tn0, tmv0, tmi0, jb);
    process_row(wv + 4, tv1, tj1, tn1, tmv1, tmi1, jb);
  }
  __syncthreads();

  if (lane == 0) {
    int row0 = m0 + wv;
#pragma unroll
    for (int s = 0; s < 10; ++s) {
      topvp[(size_t)row0 * 80 + split * 10 + s] = tv0[s];
      topip[(size_t)row0 * 80 + split * 10 + s] = tj0[s];
    }
    int row1 = m0 + wv + 4;
#pragma unroll
    for (int s = 0; s < 10; ++s) {
      topvp[(size_t)row1 * 80 + split * 10 + s] = tv1[s];
      topip[(size_t)row1 * 80 + split * 10 + s] = tj1[s];
    }
  }
}

// merge 8 splits x 10 candidates -> global top-10 per row (value desc, idx asc)
__global__ void merge_topk(const float* __restrict__ topvp, const int* __restrict__ topip,
                           float* __restrict__ topv, int* __restrict__ topi)
{
  const int wv = threadIdx.x >> 6;
  const int lane = threadIdx.x & 63;
  const int row = blockIdx.x * 4 + wv;
  float v0 = topvp[(size_t)row * 80 + lane];
  int   i0 = topip[(size_t)row * 80 + lane];
  float v1 = (lane < 16) ? topvp[(size_t)row * 80 + 64 + lane] : -INFINITY;
  int   i1 = (lane < 16) ? topip[(size_t)row * 80 + 64 + lane] : 0x7fffffff;
  for (int s = 0; s < 10; ++s) {
    float bv = v0; int bj = i0;
    if (v1 > bv || (v1 == bv && i1 < bj)) { bv = v1; bj = i1; }
#pragma unroll
    for (int o = 1; o < 64; o <<= 1) {
      float ov = __shfl_xor(bv, o, 64);
      int   oj = __shfl_xor(bj, o, 64);
      if (ov > bv || (ov == bv && oj < bj)) { bv = ov; bj = oj; }
    }
    if (lane == 0) { topv[row * 10 + s] = bv; topi[row * 10 + s] = bj; }
    if (i0 == bj) { v0 = -INFINITY; i0 = 0x7fffffff; }
    if (i1 == bj) { v1 = -INFINITY; i1 = 0x7fffffff; }
  }
}

// ---------------------------------------------------------------- final: agg + fc
__global__ void final_kernel(const float* __restrict__ mb, const float* __restrict__ kh,
                             const float* __restrict__ topv, const int* __restrict__ topi,
                             const float* __restrict__ fcW, const float* __restrict__ fcb,
                             float* __restrict__ y)
{
  __shared__ float red[256];
  int n = blockIdx.x, c = threadIdx.x;
  float agg = 0.f;
#pragma unroll
  for (int k = 0; k < 10; ++k) {
    float w = topv[n * 10 + k] / 10.0f;
    int idx = topi[n * 10 + k];
    agg += w * kh[(size_t)idx * 256 + c];
  }
  float val = fcW[c] * mb[(size_t)n * 256 + c] + fcW[256 + c] * agg;
  red[c] = val;
  __syncthreads();
  for (int o = 128; o; o >>= 1) { if (c < o) red[c] += red[c + o]; __syncthreads(); }
  if (c == 0) y[n] = red[0] + fcb[0];
}

// ---------------------------------------------------------------- launch
extern "C" void kernel_launch(void* const* d_in, const int* in_sizes, int n_in,
                              void* d_out, int out_size, void* d_ws, size_t ws_size,
                              hipStream_t stream)
{
  const float* inp    = (const float*)d_in[0];
  const float* trainh = (const float*)d_in[1];
  const float* thd    = (const float*)d_in[2];
  const float* Wih0   = (const float*)d_in[3];
  const float* Whh0   = (const float*)d_in[4];
  const float* bih0   = (const float*)d_in[5];
  const float* bhh0   = (const float*)d_in[6];
  const float* Wih1   = (const float*)d_in[7];
  const float* Whh1   = (const float*)d_in[8];
  const float* bih1   = (const float*)d_in[9];
  const float* bhh1   = (const float*)d_in[10];
  const float* lin0W  = (const float*)d_in[11];
  const float* lin0b  = (const float*)d_in[12];
  const float* lin1W  = (const float*)d_in[13];
  const float* lin1b  = (const float*)d_in[14];
  const float* lin2W  = (const float*)d_in[15];
  const float* lin2b  = (const float*)d_in[16];
  const float* p1W    = (const float*)d_in[17];
  const float* p2W    = (const float*)d_in[18];
  const float* fcW    = (const float*)d_in[19];
  const float* fcb    = (const float*)d_in[20];

  float* ws = (float*)d_ws;
  float* WT_hh0 = ws + 0;          // 256x768
  float* WTcat  = ws + 196608;     // 512x768
  float* WT_l0  = ws + 589824;     // 256x512
  float* WT_l1  = ws + 720896;     // 512x512
  float* WT_l2  = ws + 983040;     // 512x256
  float* WT_p1  = ws + 1114112;    // 256x256
  float* WT_p2  = ws + 1179648;    // 256x256
  float* hrow   = ws + 1245184;    // 2048x256
  float* mb1    = ws + 3342336;    // 2048x512 (reused for topk candidates)
  float* mb2    = ws + 4390912;    // 2048x512 (reused for mbday partials)
  float* mbf    = ws + 5439488;    // 2048x256
  float* mbday  = ws + 5963776;    // 4x256
  float* qbuf   = ws + 5964800;    // 2048x256
  float* kh     = ws + 6489088;    // 20480x256
  float* khT    = ws + 11731968;   // 256x20480 (normalized)
  float* khn    = ws + 16974848;   // 20480
  float* qn     = ws + 16995328;   // 2048
  float* topv   = ws + 16997376;   // 2048x10
  int*   dayidx = (int*)(ws + 17017856);
  int*   rowsrc = (int*)(ws + 17017920);
  int*   topi   = (int*)(ws + 17038400);
  float* topvp  = mb1;                       // 2048x80
  int*   topip  = (int*)(mb1 + 163840);      // 2048x80
  float* mbpart = mb2;                       // 4x8x256

  PrepArgs pa;
  pa.src[0] = Whh0;  pa.dst[0] = WT_hh0; pa.N[0] = 768; pa.K[0] = 256; pa.ro[0] = 0;
  pa.src[1] = Wih1;  pa.dst[1] = WTcat;  pa.N[1] = 768; pa.K[1] = 256; pa.ro[1] = 0;
  pa.src[2] = Whh1;  pa.dst[2] = WTcat;  pa.N[2] = 768; pa.K[2] = 256; pa.ro[2] = 256;
  pa.src[3] = lin0W; pa.dst[3] = WT_l0;  pa.N[3] = 512; pa.K[3] = 256; pa.ro[3] = 0;
  pa.src[4] = lin1W; pa.dst[4] = WT_l1;  pa.N[4] = 512; pa.K[4] = 512; pa.ro[4] = 0;
  pa.src[5] = lin2W; pa.dst[5] = WT_l2;  pa.N[5] = 256; pa.K[5] = 512; pa.ro[5] = 0;
  pa.src[6] = p1W;   pa.dst[6] = WT_p1;  pa.N[6] = 256; pa.K[6] = 256; pa.ro[6] = 0;
  pa.src[7] = p2W;   pa.dst[7] = WT_p2;  pa.N[7] = 256; pa.K[7] = 256; pa.ro[7] = 0;
  prep_weights<<<dim3(64, 8), dim3(256), 0, stream>>>(pa);

  gru_fused<<<256, 256, 0, stream>>>(inp, WT_hh0, WTcat, Wih0, bih0, bhh0, bih1, bhh1, hrow);

  gemm_act<<<dim3(16, 64), dim3(32, 8), 0, stream>>>(hrow, nullptr, WT_l0, lin0b, mb1, 2048, 512, 256, 1);
  gemm_act<<<dim3(16, 64), dim3(32, 8), 0, stream>>>(mb1, nullptr, WT_l1, lin1b, mb2, 2048, 512, 512, 1);
  gemm_act<<<dim3(8, 64),  dim3(32, 8), 0, stream>>>(mb2, nullptr, WT_l2, lin2b, mbf, 2048, 256, 512, 1);

  mbday_part<<<dim3(4, 8), 256, 0, stream>>>(mbf, mbpart);
  mbday_fin<<<4, 256, 0, stream>>>(mbpart, mbday);
  daytopk_kernel<<<4, 256, 0, stream>>>(mbday, thd, dayidx);
  rowsrc_kernel<<<80, 256, 0, stream>>>(dayidx, rowsrc);

  gemm_act<<<dim3(8, 640), dim3(32, 8), 0, stream>>>(trainh, rowsrc, WT_p2, nullptr, kh, 20480, 256, 256, 0);
  gemm_act<<<dim3(8, 64),  dim3(32, 8), 0, stream>>>(mbf, nullptr, WT_p1, nullptr, qbuf, 2048, 256, 256, 0);

  rownorm_kernel<<<5120, 256, 0, stream>>>(kh, khn, 20480);
  rownorm_kernel<<<512, 256, 0, stream>>>(qbuf, qn, 2048);
  qnorm_kernel<<<2048, 256, 0, stream>>>(qbuf, qn);
  khT_kernel<<<dim3(640, 8), 256, 0, stream>>>(kh, khn, khT);

  csmax_kernel<<<2048, 256, 0, stream>>>(qbuf, khT, topvp, topip);
  merge_topk<<<512, 256, 0, stream>>>(topvp, topip, topv, topi);
  final_kernel<<<2048, 256, 0, stream>>>(mbf, kh, topv, topi, fcW, fcb, (float*)d_out);

  (void)in_sizes; (void)n_in; (void)out_size; (void)ws_size;
}

// Round 5
// 3798.643 us; speedup vs baseline: 2.4027x; 1.2363x over previous
//
#include <hip/hip_runtime.h>
#include <cmath>
#include <cstdint>

#define D_FEAT 6
#define T_SEQ  60
#define HID    256
#define G3     768
#define NROW   2048
#define NSAMP  20480

__device__ __forceinline__ float sigmoidf_(float x) { return 1.0f / (1.0f + expf(-x)); }

// ---------------------------------------------------------------- weight prep
struct PrepArgs {
  const float* src[9];
  float* dst[9];
  int N[9], K[9], ro[9];
};

__global__ void prep_weights(PrepArgs a) {
  int seg = blockIdx.y;
  const float* S = a.src[seg];
  float* D = a.dst[seg];
  int N = a.N[seg], K = a.K[seg], ro = a.ro[seg];
  int total = N * K;
  for (int i = blockIdx.x * blockDim.x + threadIdx.x; i < total; i += gridDim.x * blockDim.x) {
    int n = i / K, k = i - n * K;
    D[(size_t)(k + ro) * N + n] = S[i];   // WT[k][n] = W[n][k]
  }
}

// ---------------------------------------------------------------- persistent fused GRU v2
// Grid 256 x 256 threads. Block owns 8 stocks. Thread tid owns outputs
// o = {tid, 256+tid, 512+tid} (r,z,n of column j=tid) for all 8 rows -> the
// gate computer IS the combiner: no gate exchange, gates never leave registers.
// h tiles ping-pong in LDS ([k*8+row], float4-broadcast reads). Weight reads:
// 3 coalesced dwords/thread/k = exactly-unique per CU. 2 barriers/step.
// K=256 inner loop: B ping-pong 4k-groups (>=192cyc lead), A ring-4 (>=144cyc).
__device__ __forceinline__ void kloop256(const float* __restrict__ A,   // LDS [k*8+row]
                                         const float* __restrict__ B,   // global + tid, stride 768/k
                                         float (&acc)[3][8])
{
  float4 Aa[4][2];
  float  Bb[2][12];
#pragma unroll
  for (int c = 0; c < 4; ++c) {
    Aa[c][0] = *(const float4*)(A + c * 8);
    Aa[c][1] = *(const float4*)(A + c * 8 + 4);
  }
#pragma unroll
  for (int c = 0; c < 4; ++c)
#pragma unroll
    for (int u = 0; u < 3; ++u)
      Bb[0][c * 3 + u] = B[(size_t)c * G3 + u * 256];

  for (int kb = 0; kb < 256; kb += 8) {
    // prefetch B for kb+4..kb+7
    {
      const float* p = B + (size_t)(kb + 4) * G3;
#pragma unroll
      for (int c = 0; c < 4; ++c)
#pragma unroll
        for (int u = 0; u < 3; ++u)
          Bb[1][c * 3 + u] = p[(size_t)c * G3 + u * 256];
    }
    // compute kb..kb+3; refill A ring with kb+4..kb+7
#pragma unroll
    for (int c = 0; c < 4; ++c) {
      float4 alo = Aa[c][0], ahi = Aa[c][1];
      int kn = kb + 4 + c;                 // max 255
      Aa[c][0] = *(const float4*)(A + kn * 8);
      Aa[c][1] = *(const float4*)(A + kn * 8 + 4);
#pragma unroll
      for (int u = 0; u < 3; ++u) {
        float b = Bb[0][c * 3 + u];
        acc[u][0] += alo.x * b; acc[u][1] += alo.y * b;
        acc[u][2] += alo.z * b; acc[u][3] += alo.w * b;
        acc[u][4] += ahi.x * b; acc[u][5] += ahi.y * b;
        acc[u][6] += ahi.z * b; acc[u][7] += ahi.w * b;
      }
    }
    // prefetch B for next block (wrap-guarded; last prefetch unused)
    {
      int kw = (kb + 8) & 255;
      const float* p = B + (size_t)kw * G3;
#pragma unroll
      for (int c = 0; c < 4; ++c)
#pragma unroll
        for (int u = 0; u < 3; ++u)
          Bb[0][c * 3 + u] = p[(size_t)c * G3 + u * 256];
    }
    // compute kb+4..kb+7; refill A ring (wrap)
#pragma unroll
    for (int c = 0; c < 4; ++c) {
      float4 alo = Aa[c][0], ahi = Aa[c][1];
      int kn = (kb + 8 + c) & 255;
      Aa[c][0] = *(const float4*)(A + kn * 8);
      Aa[c][1] = *(const float4*)(A + kn * 8 + 4);
#pragma unroll
      for (int u = 0; u < 3; ++u) {
        float b = Bb[1][c * 3 + u];
        acc[u][0] += alo.x * b; acc[u][1] += alo.y * b;
        acc[u][2] += alo.z * b; acc[u][3] += alo.w * b;
        acc[u][4] += ahi.x * b; acc[u][5] += ahi.y * b;
        acc[u][6] += ahi.z * b; acc[u][7] += ahi.w * b;
      }
    }
  }
}

__global__ __launch_bounds__(256, 1)
void gru_fused(const float* __restrict__ inp, const float* __restrict__ WThh0,
               const float* __restrict__ WTcat, const float* __restrict__ WTih0,
               const float* __restrict__ bih0, const float* __restrict__ bhh0,
               const float* __restrict__ bih1, const float* __restrict__ bhh1,
               float* __restrict__ hrow)
{
  __shared__ float h0A[2048], h0B[2048];   // [k*8+row] ping-pong
  __shared__ float h1A[2048], h1B[2048];
  __shared__ float xls[2880];              // [(i*60+t)*8 + row]

  const int tid = threadIdx.x;
  const int m0 = blockIdx.x * 8;

  for (int c = tid; c < 2880; c += 256) {
    int row = c / 360, it = c - row * 360;
    xls[it * 8 + row] = inp[(size_t)(m0 + row) * 360 + it];
  }
  for (int c = tid; c < 2048; c += 256) { h0A[c] = 0.f; h1A[c] = 0.f; }

  float h0c[8], h1c[8];
#pragma unroll
  for (int r = 0; r < 8; ++r) { h0c[r] = 0.f; h1c[r] = 0.f; }

  float b_ih0[3], b_hh0[3], b_ih1[3], b_hh1[3];
#pragma unroll
  for (int u = 0; u < 3; ++u) {
    int o = u * 256 + tid;
    b_ih0[u] = bih0[o]; b_hh0[u] = bhh0[o];
    b_ih1[u] = bih1[o]; b_hh1[u] = bhh1[o];
  }
  __syncthreads();

  const float* Bhh0 = WThh0 + tid;
  const float* Bc0  = WTcat + tid;
  const float* Bc1  = WTcat + (size_t)256 * G3 + tid;

  for (int t = 0; t < T_SEQ; ++t) {
    const float* h0cur = (t & 1) ? h0B : h0A;
    float*       h0nxt = (t & 1) ? h0A : h0B;
    const float* h1cur = (t & 1) ? h1B : h1A;
    float*       h1nxt = (t & 1) ? h1A : h1B;

    // ================= layer 0 =================
    float xw[3][8];
#pragma unroll
    for (int u = 0; u < 3; ++u)
#pragma unroll
      for (int r = 0; r < 8; ++r) xw[u][r] = b_ih0[u];
#pragma unroll
    for (int i = 0; i < 6; ++i) {
      float4 xlo = *(const float4*)&xls[(i * 60 + t) * 8];
      float4 xhi = *(const float4*)&xls[(i * 60 + t) * 8 + 4];
#pragma unroll
      for (int u = 0; u < 3; ++u) {
        float b = WTih0[i * G3 + u * 256 + tid];
        xw[u][0] += xlo.x * b; xw[u][1] += xlo.y * b;
        xw[u][2] += xlo.z * b; xw[u][3] += xlo.w * b;
        xw[u][4] += xhi.x * b; xw[u][5] += xhi.y * b;
        xw[u][6] += xhi.z * b; xw[u][7] += xhi.w * b;
      }
    }
    float gh[3][8];
#pragma unroll
    for (int u = 0; u < 3; ++u)
#pragma unroll
      for (int r = 0; r < 8; ++r) gh[u][r] = 0.f;
    kloop256(h0cur, Bhh0, gh);

    {
      float hn[8];
#pragma unroll
      for (int r = 0; r < 8; ++r) {
        float rr = sigmoidf_(xw[0][r] + (gh[0][r] + b_hh0[0]));
        float zz = sigmoidf_(xw[1][r] + (gh[1][r] + b_hh0[1]));
        float nn = tanhf(xw[2][r] + rr * (gh[2][r] + b_hh0[2]));
        h0c[r] = (1.f - zz) * nn + zz * h0c[r];
        hn[r] = h0c[r];
      }
      *(float4*)&h0nxt[tid * 8]     = *(float4*)&hn[0];
      *(float4*)&h0nxt[tid * 8 + 4] = *(float4*)&hn[4];
    }
    __syncthreads();

    // ================= layer 1 =================
    float acc[3][8];
#pragma unroll
    for (int u = 0; u < 3; ++u)
#pragma unroll
      for (int r = 0; r < 8; ++r) acc[u][r] = 0.f;
    kloop256(h0nxt, Bc0, acc);          // x-part (K=256 over new h0)
    float xn8[8];
#pragma unroll
    for (int r = 0; r < 8; ++r) { xn8[r] = acc[2][r]; acc[2][r] = 0.f; }
    kloop256(h1cur, Bc1, acc);          // h-part: r/z continue, n fresh

    {
      float hn[8];
#pragma unroll
      for (int r = 0; r < 8; ++r) {
        float rr = sigmoidf_((acc[0][r] + b_ih1[0]) + b_hh1[0]);
        float zz = sigmoidf_((acc[1][r] + b_ih1[1]) + b_hh1[1]);
        float nn = tanhf((xn8[r] + b_ih1[2]) + rr * (acc[2][r] + b_hh1[2]));
        h1c[r] = (1.f - zz) * nn + zz * h1c[r];
        hn[r] = h1c[r];
      }
      *(float4*)&h1nxt[tid * 8]     = *(float4*)&hn[0];
      *(float4*)&h1nxt[tid * 8 + 4] = *(float4*)&hn[4];
    }
    __syncthreads();
  }

#pragma unroll
  for (int r = 0; r < 8; ++r)
    hrow[(size_t)(m0 + r) * 256 + tid] = h1c[r];
}

// ---------------------------------------------------------------- generic GEMM
__global__ __launch_bounds__(256, 2)
void gemm_act(const float* __restrict__ A, const int* __restrict__ rowsrc,
              const float* __restrict__ WT, const float* __restrict__ bias,
              float* __restrict__ C, int M, int N, int K, int act)
{
  __shared__ float4 As4[128 * 32];
  const int tx = threadIdx.x, ty = threadIdx.y;
  const int tid = ty * 32 + tx;
  const int n0 = blockIdx.x * 32, m0 = blockIdx.y * 32;
  const int K4 = K >> 2;

  for (int c = tid; c < K4 * 32; c += 256) {
    int k4 = c % K4, m = c / K4;
    int row = m0 + m;
    if (rowsrc) row = rowsrc[row];
    As4[k4 * 32 + m] = *(const float4*)(A + (size_t)row * K + k4 * 4);
  }
  __syncthreads();

  float acc[4] = {0,0,0,0};
  const int n = n0 + tx;
  const float* pb = WT + n;

  float bc[4], bn_[4];
#pragma unroll
  for (int kk = 0; kk < 4; ++kk) bc[kk] = pb[(size_t)kk * N];
  for (int k4 = 0; k4 < K4; ++k4) {
    int nk4 = (k4 + 1 < K4) ? (k4 + 1) : 0;
    const float* pn = pb + (size_t)nk4 * 4 * N;
#pragma unroll
    for (int kk = 0; kk < 4; ++kk) bn_[kk] = pn[(size_t)kk * N];
    float4 a0 = As4[k4 * 32 + ty * 4 + 0];
    float4 a1 = As4[k4 * 32 + ty * 4 + 1];
    float4 a2 = As4[k4 * 32 + ty * 4 + 2];
    float4 a3 = As4[k4 * 32 + ty * 4 + 3];
#pragma unroll
    for (int kk = 0; kk < 4; ++kk) {
      float b = bc[kk];
      acc[0] += ((const float*)&a0)[kk] * b;
      acc[1] += ((const float*)&a1)[kk] * b;
      acc[2] += ((const float*)&a2)[kk] * b;
      acc[3] += ((const float*)&a3)[kk] * b;
    }
#pragma unroll
    for (int q = 0; q < 4; ++q) bc[q] = bn_[q];
  }
  float bb = bias ? bias[n] : 0.f;
#pragma unroll
  for (int r = 0; r < 4; ++r) {
    float v = acc[r] + bb;
    if (act) v = (v >= 0.f) ? v : 0.01f * v;
    C[(size_t)(m0 + ty * 4 + r) * N + n] = v;
  }
}

// ---------------------------------------------------------------- small stages
__global__ void mbday_part(const float* __restrict__ mbf, float* __restrict__ part) {
  int d = blockIdx.x, sl = blockIdx.y, c = threadIdx.x;
  float s = 0.f;
  int base = d * 512 + sl * 64;
  for (int st = 0; st < 64; ++st) s += mbf[(size_t)(base + st) * 256 + c];
  part[(size_t)(d * 8 + sl) * 256 + c] = s;
}

__global__ void mbday_fin(const float* __restrict__ part, float* __restrict__ mbday) {
  int d = blockIdx.x, c = threadIdx.x;
  float s = 0.f;
#pragma unroll
  for (int p = 0; p < 8; ++p) s += part[(size_t)(d * 8 + p) * 256 + c];
  mbday[d * 256 + c] = s * (1.0f / 512.0f);
}

__global__ void daytopk_kernel(const float* __restrict__ mbday, const float* __restrict__ thd,
                               int* __restrict__ dayidx) {
  __shared__ float mbs[256];
  __shared__ float sim[256];
  __shared__ float red[256];
  __shared__ int   redi[256];
  const int d = blockIdx.x, t = threadIdx.x;
  mbs[t] = mbday[d * 256 + t];
  __syncthreads();
  red[t] = mbs[t] * mbs[t];
  __syncthreads();
  for (int o = 128; o; o >>= 1) { if (t < o) red[t] += red[t + o]; __syncthreads(); }
  float xn = sqrtf(red[0]);
  float v = -INFINITY;
  if (t < 240) {
    float dot = 0.f, yn2 = 0.f;
    for (int k = 0; k < 256; ++k) {
      float y = thd[t * 256 + k];
      dot += mbs[k] * y;
      yn2 += y * y;
    }
    float den = xn * sqrtf(yn2);
    v = (den > 0.f) ? dot / den : 0.f;
  }
  sim[t] = v;
  __syncthreads();
  for (int it = 0; it < 10; ++it) {
    red[t] = sim[t]; redi[t] = t;
    __syncthreads();
    for (int o = 128; o; o >>= 1) {
      if (t < o) {
        if (red[t + o] > red[t] || (red[t + o] == red[t] && redi[t + o] < redi[t])) {
          red[t] = red[t + o]; redi[t] = redi[t + o];
        }
      }
      __syncthreads();
    }
    if (t == 0) { int bi = redi[0]; dayidx[d * 10 + it] = bi; sim[bi] = -INFINITY; }
    __syncthreads();
  }
}

__global__ void rowsrc_kernel(const int* __restrict__ dayidx, int* __restrict__ rowsrc) {
  int r = blockIdx.x * 256 + threadIdx.x;
  if (r < NSAMP) rowsrc[r] = dayidx[r >> 9] * 512 + (r & 511);
}

__global__ void rownorm_kernel(const float* __restrict__ X, float* __restrict__ out, int rows) {
  int w = threadIdx.x >> 6;
  int lane = threadIdx.x & 63;
  int row = blockIdx.x * 4 + w;
  if (row >= rows) return;
  float4 x = *(const float4*)(X + (size_t)row * 256 + lane * 4);
  float s = x.x * x.x + x.y * x.y + x.z * x.z + x.w * x.w;
#pragma unroll
  for (int o = 32; o; o >>= 1) s += __shfl_down(s, o, 64);
  if (lane == 0) out[row] = sqrtf(s);
}

__global__ void qnorm_kernel(float* __restrict__ q, const float* __restrict__ qn) {
  int i = blockIdx.x * 256 + threadIdx.x;
  int row = i >> 8;
  float n = qn[row];
  q[i] = (n > 0.f) ? q[i] / n : 0.f;
}

__global__ void khT_kernel(const float* __restrict__ kh, const float* __restrict__ khn,
                           float* __restrict__ khT) {
  __shared__ float tile[32][33];
  int jb = blockIdx.x * 32;
  int kb = blockIdx.y * 32;
  int tx = threadIdx.x & 31, tyy = threadIdx.x >> 5;
  for (int rr = tyy; rr < 32; rr += 8) {
    float n = khn[jb + rr];
    float v = kh[(size_t)(jb + rr) * 256 + kb + tx];
    tile[rr][tx] = (n > 0.f) ? v / n : 0.f;
  }
  __syncthreads();
  for (int rr = tyy; rr < 32; rr += 8) {
    khT[(size_t)(kb + rr) * NSAMP + jb + tx] = tile[tx][rr];
  }
}

// ---------------------------------------------------------------- cs GEMM + top-10 (split, XCD-swizzled)
__global__ __launch_bounds__(256, 4)
void csmax_kernel(const float* __restrict__ qh, const float* __restrict__ khT,
                  float* __restrict__ topvp, int* __restrict__ topip)
{
  __shared__ float4 qs[256][2];
  __shared__ float csch[8 * 512];
  const int tid = threadIdx.x;
  const int split = blockIdx.x & 7;
  const int m0 = (blockIdx.x >> 3) * 8;
  {
    int k = tid;
    float4 v0, v1;
    v0.x = qh[(size_t)(m0 + 0) * 256 + k]; v0.y = qh[(size_t)(m0 + 1) * 256 + k];
    v0.z = qh[(size_t)(m0 + 2) * 256 + k]; v0.w = qh[(size_t)(m0 + 3) * 256 + k];
    v1.x = qh[(size_t)(m0 + 4) * 256 + k]; v1.y = qh[(size_t)(m0 + 5) * 256 + k];
    v1.z = qh[(size_t)(m0 + 6) * 256 + k]; v1.w = qh[(size_t)(m0 + 7) * 256 + k];
    qs[k][0] = v0; qs[k][1] = v1;
  }
  __syncthreads();
  const int lane = tid & 63;
  const int wv = tid >> 6;

  float tv0[10], tv1[10];
  int   tj0[10], tj1[10];
  int   tn0 = 0, tn1 = 0;
  float tmv0 = -INFINITY, tmv1 = -INFINITY;
  int   tmi0 = 0, tmi1 = 0;

  auto process_row = [&](int r, float (&tv)[10], int (&tj)[10], int& tn,
                         float& tmv, int& tmi, int jb) {
    float4 c0 = *(const float4*)&csch[r * 512 + lane * 8];
    float4 c1 = *(const float4*)&csch[r * 512 + lane * 8 + 4];
    float cv[8] = {c0.x, c0.y, c0.z, c0.w, c1.x, c1.y, c1.z, c1.w};
    const int cj0 = jb + lane * 8;
    while (true) {
      float bv = -INFINITY; int bj = 0x7fffffff;
#pragma unroll
      for (int u = 0; u < 8; ++u) {
        if (cv[u] > bv) { bv = cv[u]; bj = cj0 + u; }
      }
#pragma unroll
      for (int o = 32; o; o >>= 1) {
        float ov = __shfl_down(bv, o, 64);
        int   oj = __shfl_down(bj, o, 64);
        if (ov > bv || (ov == bv && oj < bj)) { bv = ov; bj = oj; }
      }
      bv = __shfl(bv, 0, 64); bj = __shfl(bj, 0, 64);
      bool take;
      if (tn < 10) take = true;
      else take = (bv > tmv) || (bv == tmv && bj < tmi);
      if (!take) break;
      if (tn < 10) {
#pragma unroll
        for (int s = 0; s < 10; ++s) if (s == tn) { tv[s] = bv; tj[s] = bj; }
        tn++;
        if (tn == 10) {
          float mv = tv[0]; int mi = tj[0];
#pragma unroll
          for (int s = 1; s < 10; ++s) {
            bool w = (tv[s] < mv) || (tv[s] == mv && tj[s] > mi);
            if (w) { mv = tv[s]; mi = tj[s]; }
          }
          tmv = mv; tmi = mi;
        }
      } else {
        int ms = 0; float mv = tv[0]; int mi = tj[0];
#pragma unroll
        for (int s = 1; s < 10; ++s) {
          bool w = (tv[s] < mv) || (tv[s] == mv && tj[s] > mi);
          if (w) { ms = s; mv = tv[s]; mi = tj[s]; }
        }
#pragma unroll
        for (int s = 0; s < 10; ++s) if (s == ms) { tv[s] = bv; tj[s] = bj; }
        mv = tv[0]; mi = tj[0];
#pragma unroll
        for (int s = 1; s < 10; ++s) {
          bool w = (tv[s] < mv) || (tv[s] == mv && tj[s] > mi);
          if (w) { mv = tv[s]; mi = tj[s]; }
        }
        tmv = mv; tmi = mi;
      }
#pragma unroll
      for (int u = 0; u < 8; ++u) if (cj0 + u == bj) cv[u] = -INFINITY;
    }
  };

  for (int ci = 0; ci < 5; ++ci) {
    const int ch = split * 5 + ci;
    const int jb = ch * 512;
    float acc[8][2];
#pragma unroll
    for (int r = 0; r < 8; ++r) { acc[r][0] = 0.f; acc[r][1] = 0.f; }
    const float* kp = khT + jb + tid;

    float b0c[4], b1c[4], b0n[4], b1n[4];
#pragma unroll
    for (int kk = 0; kk < 4; ++kk) {
      b0c[kk] = kp[(size_t)kk * NSAMP];
      b1c[kk] = kp[(size_t)kk * NSAMP + 256];
    }
    for (int k4 = 0; k4 < 64; ++k4) {
      int nk4 = (k4 + 1) & 63;
      const float* pn = kp + (size_t)nk4 * 4 * NSAMP;
#pragma unroll
      for (int kk = 0; kk < 4; ++kk) {
        b0n[kk] = pn[(size_t)kk * NSAMP];
        b1n[kk] = pn[(size_t)kk * NSAMP + 256];
      }
#pragma unroll
      for (int kk = 0; kk < 4; ++kk) {
        float4 qa = qs[k4 * 4 + kk][0];
        float4 qb = qs[k4 * 4 + kk][1];
        float b0 = b0c[kk], b1 = b1c[kk];
        acc[0][0] += qa.x * b0; acc[1][0] += qa.y * b0; acc[2][0] += qa.z * b0; acc[3][0] += qa.w * b0;
        acc[4][0] += qb.x * b0; acc[5][0] += qb.y * b0; acc[6][0] += qb.z * b0; acc[7][0] += qb.w * b0;
        acc[0][1] += qa.x * b1; acc[1][1] += qa.y * b1; acc[2][1] += qa.z * b1; acc[3][1] += qa.w * b1;
        acc[4][1] += qb.x * b1; acc[5][1] += qb.y * b1; acc[6][1] += qb.z * b1; acc[7][1] += qb.w * b1;
      }
#pragma unroll
      for (int q = 0; q < 4; ++q) { b0c[q] = b0n[q]; b1c[q] = b1n[q]; }
    }
    __syncthreads();
#pragma unroll
    for (int r = 0; r < 8; ++r) {
      csch[r * 512 + tid] = acc[r][0];
      csch[r * 512 + 256 + tid] = acc[r][1];
    }
    __syncthreads();
    process_row(wv,     tv0, tj0, tn0, tmv0, tmi0, jb);
    process_row(wv + 4, tv1, tj1, tn1, tmv1, tmi1, jb);
  }
  __syncthreads();

  if (lane == 0) {
    int row0 = m0 + wv;
#pragma unroll
    for (int s = 0; s < 10; ++s) {
      topvp[(size_t)row0 * 80 + split * 10 + s] = tv0[s];
      topip[(size_t)row0 * 80 + split * 10 + s] = tj0[s];
    }
    int row1 = m0 + wv + 4;
#pragma unroll
    for (int s = 0; s < 10; ++s) {
      topvp[(size_t)row1 * 80 + split * 10 + s] = tv1[s];
      topip[(size_t)row1 * 80 + split * 10 + s] = tj1[s];
    }
  }
}

// merge 8 splits x 10 candidates -> global top-10 per row (value desc, idx asc)
__global__ void merge_topk(const float* __restrict__ topvp, const int* __restrict__ topip,
                           float* __restrict__ topv, int* __restrict__ topi)
{
  const int wv = threadIdx.x >> 6;
  const int lane = threadIdx.x & 63;
  const int row = blockIdx.x * 4 + wv;
  float v0 = topvp[(size_t)row * 80 + lane];
  int   i0 = topip[(size_t)row * 80 + lane];
  float v1 = (lane < 16) ? topvp[(size_t)row * 80 + 64 + lane] : -INFINITY;
  int   i1 = (lane < 16) ? topip[(size_t)row * 80 + 64 + lane] : 0x7fffffff;
  for (int s = 0; s < 10; ++s) {
    float bv = v0; int bj = i0;
    if (v1 > bv || (v1 == bv && i1 < bj)) { bv = v1; bj = i1; }
#pragma unroll
    for (int o = 1; o < 64; o <<= 1) {
      float ov = __shfl_xor(bv, o, 64);
      int   oj = __shfl_xor(bj, o, 64);
      if (ov > bv || (ov == bv && oj < bj)) { bv = ov; bj = oj; }
    }
    if (lane == 0) { topv[row * 10 + s] = bv; topi[row * 10 + s] = bj; }
    if (i0 == bj) { v0 = -INFINITY; i0 = 0x7fffffff; }
    if (i1 == bj) { v1 = -INFINITY; i1 = 0x7fffffff; }
  }
}

// ---------------------------------------------------------------- final: agg + fc
__global__ void final_kernel(const float* __restrict__ mb, const float* __restrict__ kh,
                             const float* __restrict__ topv, const int* __restrict__ topi,
                             const float* __restrict__ fcW, const float* __restrict__ fcb,
                             float* __restrict__ y)
{
  __shared__ float red[256];
  int n = blockIdx.x, c = threadIdx.x;
  float agg = 0.f;
#pragma unroll
  for (int k = 0; k < 10; ++k) {
    float w = topv[n * 10 + k] / 10.0f;
    int idx = topi[n * 10 + k];
    agg += w * kh[(size_t)idx * 256 + c];
  }
  float val = fcW[c] * mb[(size_t)n * 256 + c] + fcW[256 + c] * agg;
  red[c] = val;
  __syncthreads();
  for (int o = 128; o; o >>= 1) { if (c < o) red[c] += red[c + o]; __syncthreads(); }
  if (c == 0) y[n] = red[0] + fcb[0];
}

// ---------------------------------------------------------------- launch
extern "C" void kernel_launch(void* const* d_in, const int* in_sizes, int n_in,
                              void* d_out, int out_size, void* d_ws, size_t ws_size,
                              hipStream_t stream)
{
  const float* inp    = (const float*)d_in[0];
  const float* trainh = (const float*)d_in[1];
  const float* thd    = (const float*)d_in[2];
  const float* Wih0   = (const float*)d_in[3];
  const float* Whh0   = (const float*)d_in[4];
  const float* bih0   = (const float*)d_in[5];
  const float* bhh0   = (const float*)d_in[6];
  const float* Wih1   = (const float*)d_in[7];
  const float* Whh1   = (const float*)d_in[8];
  const float* bih1   = (const float*)d_in[9];
  const float* bhh1   = (const float*)d_in[10];
  const float* lin0W  = (const float*)d_in[11];
  const float* lin0b  = (const float*)d_in[12];
  const float* lin1W  = (const float*)d_in[13];
  const float* lin1b  = (const float*)d_in[14];
  const float* lin2W  = (const float*)d_in[15];
  const float* lin2b  = (const float*)d_in[16];
  const float* p1W    = (const float*)d_in[17];
  const float* p2W    = (const float*)d_in[18];
  const float* fcW    = (const float*)d_in[19];
  const float* fcb    = (const float*)d_in[20];

  float* ws = (float*)d_ws;
  float* WT_hh0 = ws + 0;          // 256x768
  float* WTcat  = ws + 196608;     // 512x768
  float* WT_l0  = ws + 589824;     // 256x512
  float* WT_l1  = ws + 720896;     // 512x512
  float* WT_l2  = ws + 983040;     // 512x256
  float* WT_p1  = ws + 1114112;    // 256x256
  float* WT_p2  = ws + 1179648;    // 256x256
  float* hrow   = ws + 1245184;    // 2048x256
  float* mb1    = ws + 3342336;    // 2048x512 (reused for topk candidates)
  float* mb2    = ws + 4390912;    // 2048x512 (WT_ih0 during GRU; mbday partials later)
  float* mbf    = ws + 5439488;    // 2048x256
  float* mbday  = ws + 5963776;    // 4x256
  float* qbuf   = ws + 5964800;    // 2048x256
  float* kh     = ws + 6489088;    // 20480x256
  float* khT    = ws + 11731968;   // 256x20480 (normalized)
  float* khn    = ws + 16974848;   // 20480
  float* qn     = ws + 16995328;   // 2048
  float* topv   = ws + 16997376;   // 2048x10
  int*   dayidx = (int*)(ws + 17017856);
  int*   rowsrc = (int*)(ws + 17017920);
  int*   topi   = (int*)(ws + 17038400);
  float* topvp  = mb1;                       // 2048x80
  int*   topip  = (int*)(mb1 + 163840);      // 2048x80
  float* WT_ih0 = mb2;                       // 6x768 (used only during gru_fused)
  float* mbpart = mb2;                       // 4x8x256 (after GRU)

  PrepArgs pa;
  pa.src[0] = Whh0;  pa.dst[0] = WT_hh0; pa.N[0] = 768; pa.K[0] = 256; pa.ro[0] = 0;
  pa.src[1] = Wih1;  pa.dst[1] = WTcat;  pa.N[1] = 768; pa.K[1] = 256; pa.ro[1] = 0;
  pa.src[2] = Whh1;  pa.dst[2] = WTcat;  pa.N[2] = 768; pa.K[2] = 256; pa.ro[2] = 256;
  pa.src[3] = lin0W; pa.dst[3] = WT_l0;  pa.N[3] = 512; pa.K[3] = 256; pa.ro[3] = 0;
  pa.src[4] = lin1W; pa.dst[4] = WT_l1;  pa.N[4] = 512; pa.K[4] = 512; pa.ro[4] = 0;
  pa.src[5] = lin2W; pa.dst[5] = WT_l2;  pa.N[5] = 256; pa.K[5] = 512; pa.ro[5] = 0;
  pa.src[6] = p1W;   pa.dst[6] = WT_p1;  pa.N[6] = 256; pa.K[6] = 256; pa.ro[6] = 0;
  pa.src[7] = p2W;   pa.dst[7] = WT_p2;  pa.N[7] = 256; pa.K[7] = 256; pa.ro[7] = 0;
  pa.src[8] = Wih0;  pa.dst[8] = WT_ih0; pa.N[8] = 768; pa.K[8] = 6;   pa.ro[8] = 0;
  prep_weights<<<dim3(64, 9), dim3(256), 0, stream>>>(pa);

  gru_fused<<<256, 256, 0, stream>>>(inp, WT_hh0, WTcat, WT_ih0, bih0, bhh0, bih1, bhh1, hrow);

  gemm_act<<<dim3(16, 64), dim3(32, 8), 0, stream>>>(hrow, nullptr, WT_l0, lin0b, mb1, 2048, 512, 256, 1);
  gemm_act<<<dim3(16, 64), dim3(32, 8), 0, stream>>>(mb1, nullptr, WT_l1, lin1b, mb2, 2048, 512, 512, 1);
  gemm_act<<<dim3(8, 64),  dim3(32, 8), 0, stream>>>(mb2, nullptr, WT_l2, lin2b, mbf, 2048, 256, 512, 1);

  mbday_part<<<dim3(4, 8), 256, 0, stream>>>(mbf, mbpart);
  mbday_fin<<<4, 256, 0, stream>>>(mbpart, mbday);
  daytopk_kernel<<<4, 256, 0, stream>>>(mbday, thd, dayidx);
  rowsrc_kernel<<<80, 256, 0, stream>>>(dayidx, rowsrc);

  gemm_act<<<dim3(8, 640), dim3(32, 8), 0, stream>>>(trainh, rowsrc, WT_p2, nullptr, kh, 20480, 256, 256, 0);
  gemm_act<<<dim3(8, 64),  dim3(32, 8), 0, stream>>>(mbf, nullptr, WT_p1, nullptr, qbuf, 2048, 256, 256, 0);

  rownorm_kernel<<<5120, 256, 0, stream>>>(kh, khn, 20480);
  rownorm_kernel<<<512, 256, 0, stream>>>(qbuf, qn, 2048);
  qnorm_kernel<<<2048, 256, 0, stream>>>(qbuf, qn);
  khT_kernel<<<dim3(640, 8), 256, 0, stream>>>(kh, khn, khT);

  csmax_kernel<<<2048, 256, 0, stream>>>(qbuf, khT, topvp, topip);
  merge_topk<<<512, 256, 0, stream>>>(topvp, topip, topv, topi);
  final_kernel<<<2048, 256, 0, stream>>>(mbf, kh, topv, topi, fcW, fcb, (float*)d_out);

  (void)in_sizes; (void)n_in; (void)out_size; (void)ws_size;
}

// Round 6
// 3283.076 us; speedup vs baseline: 2.7800x; 1.1570x over previous
//
#include <hip/hip_runtime.h>
#include <cmath>
#include <cstdint>

#define D_FEAT 6
#define T_SEQ  60
#define HID    256
#define G3     768
#define NROW   2048
#define NSAMP  20480

__device__ __forceinline__ float sigmoidf_(float x) { return 1.0f / (1.0f + expf(-x)); }

// ---------------------------------------------------------------- weight prep
struct PrepArgs {
  const float* src[9];
  float* dst[9];
  int N[9], K[9], ro[9];
};

__global__ void prep_weights(PrepArgs a) {
  int seg = blockIdx.y;
  const float* S = a.src[seg];
  float* D = a.dst[seg];
  int N = a.N[seg], K = a.K[seg], ro = a.ro[seg];
  int total = N * K;
  for (int i = blockIdx.x * blockDim.x + threadIdx.x; i < total; i += gridDim.x * blockDim.x) {
    int n = i / K, k = i - n * K;
    D[(size_t)(k + ro) * N + n] = S[i];   // WT[k][n] = W[n][k]
  }
}

// ---------------------------------------------------------------- persistent fused GRU v3
// Grid 256 x 512 threads (2 waves/SIMD for latency hiding). Block owns 8 stocks.
// Thread (col = tid&255, half = tid>>8) computes the half-K partial of outputs
// o = {col, 256+col, 512+col} for all 8 rows. Partials exchanged via pitch-33
// LDS once per layer; half 0 applies gates and writes h. 4 barriers/step.
__device__ __forceinline__ void kloop128(const float* __restrict__ A,   // LDS [k*8+row] (half-base)
                                         const float* __restrict__ B,   // global + col (half-base)
                                         float (&acc)[3][8])
{
  float4 Aa[4][2];
  float  Bb[2][12];
#pragma unroll
  for (int c = 0; c < 4; ++c) {
    Aa[c][0] = *(const float4*)(A + c * 8);
    Aa[c][1] = *(const float4*)(A + c * 8 + 4);
  }
#pragma unroll
  for (int c = 0; c < 4; ++c)
#pragma unroll
    for (int u = 0; u < 3; ++u)
      Bb[0][c * 3 + u] = B[(size_t)c * G3 + u * 256];

  for (int kb = 0; kb < 128; kb += 8) {
    {
      const float* p = B + (size_t)(kb + 4) * G3;
#pragma unroll
      for (int c = 0; c < 4; ++c)
#pragma unroll
        for (int u = 0; u < 3; ++u)
          Bb[1][c * 3 + u] = p[(size_t)c * G3 + u * 256];
    }
#pragma unroll
    for (int c = 0; c < 4; ++c) {
      float4 alo = Aa[c][0], ahi = Aa[c][1];
      int kn = kb + 4 + c;                 // max 127
      Aa[c][0] = *(const float4*)(A + kn * 8);
      Aa[c][1] = *(const float4*)(A + kn * 8 + 4);
#pragma unroll
      for (int u = 0; u < 3; ++u) {
        float b = Bb[0][c * 3 + u];
        acc[u][0] += alo.x * b; acc[u][1] += alo.y * b;
        acc[u][2] += alo.z * b; acc[u][3] += alo.w * b;
        acc[u][4] += ahi.x * b; acc[u][5] += ahi.y * b;
        acc[u][6] += ahi.z * b; acc[u][7] += ahi.w * b;
      }
    }
    {
      int kw = (kb + 8) & 127;
      const float* p = B + (size_t)kw * G3;
#pragma unroll
      for (int c = 0; c < 4; ++c)
#pragma unroll
        for (int u = 0; u < 3; ++u)
          Bb[0][c * 3 + u] = p[(size_t)c * G3 + u * 256];
    }
#pragma unroll
    for (int c = 0; c < 4; ++c) {
      float4 alo = Aa[c][0], ahi = Aa[c][1];
      int kn = (kb + 8 + c) & 127;
      Aa[c][0] = *(const float4*)(A + kn * 8);
      Aa[c][1] = *(const float4*)(A + kn * 8 + 4);
#pragma unroll
      for (int u = 0; u < 3; ++u) {
        float b = Bb[1][c * 3 + u];
        acc[u][0] += alo.x * b; acc[u][1] += alo.y * b;
        acc[u][2] += alo.z * b; acc[u][3] += alo.w * b;
        acc[u][4] += ahi.x * b; acc[u][5] += ahi.y * b;
        acc[u][6] += ahi.z * b; acc[u][7] += ahi.w * b;
      }
    }
  }
}

__global__ __launch_bounds__(512, 1)
void gru_fused(const float* __restrict__ inp, const float* __restrict__ WThh0,
               const float* __restrict__ WTcat, const float* __restrict__ WTih0,
               const float* __restrict__ bih0, const float* __restrict__ bhh0,
               const float* __restrict__ bih1, const float* __restrict__ bhh1,
               float* __restrict__ hrow)
{
  __shared__ float h0A[2048], h0B[2048];   // [k*8+row] ping-pong
  __shared__ float h1A[2048], h1B[2048];
  __shared__ float xls[2880];              // [(i*60+t)*8 + row]
  __shared__ float exch[256 * 33];         // pitch 33: bank-free partial exchange

  const int tid = threadIdx.x;
  const int col = tid & 255;
  const int half = tid >> 8;
  const int m0 = blockIdx.x * 8;

  for (int c = tid; c < 2880; c += 512) {
    int row = c / 360, it = c - row * 360;
    xls[it * 8 + row] = inp[(size_t)(m0 + row) * 360 + it];
  }
  for (int c = tid; c < 2048; c += 512) { h0A[c] = 0.f; h1A[c] = 0.f; }

  float h0c[8], h1c[8];                    // live on half 0 only
#pragma unroll
  for (int r = 0; r < 8; ++r) { h0c[r] = 0.f; h1c[r] = 0.f; }

  float b_ih0[3], b_hh0[3], b_ih1[3], b_hh1[3];
#pragma unroll
  for (int u = 0; u < 3; ++u) {
    int o = u * 256 + col;
    b_ih0[u] = bih0[o]; b_hh0[u] = bhh0[o];
    b_ih1[u] = bih1[o]; b_hh1[u] = bhh1[o];
  }
  __syncthreads();

  const int aoff = half * 1024;            // half*128 k-rows * 8
  const float* Bhh0 = WThh0 + (size_t)(half * 128) * G3 + col;
  const float* Bc0  = WTcat + (size_t)(half * 128) * G3 + col;
  const float* Bc1  = WTcat + (size_t)(256 + half * 128) * G3 + col;
  float* exc = exch + col * 33;

  for (int t = 0; t < T_SEQ; ++t) {
    const float* h0cur = (t & 1) ? h0B : h0A;
    float*       h0nxt = (t & 1) ? h0A : h0B;
    const float* h1cur = (t & 1) ? h1B : h1A;
    float*       h1nxt = (t & 1) ? h1A : h1B;

    // ================= layer 0 =================
    float gh[3][8];
#pragma unroll
    for (int u = 0; u < 3; ++u)
#pragma unroll
      for (int r = 0; r < 8; ++r) gh[u][r] = 0.f;
    kloop128(h0cur + aoff, Bhh0, gh);

    float xw[3][8];
    if (half == 0) {
#pragma unroll
      for (int u = 0; u < 3; ++u)
#pragma unroll
        for (int r = 0; r < 8; ++r) xw[u][r] = b_ih0[u];
#pragma unroll
      for (int i = 0; i < 6; ++i) {
        float4 xlo = *(const float4*)&xls[(i * 60 + t) * 8];
        float4 xhi = *(const float4*)&xls[(i * 60 + t) * 8 + 4];
#pragma unroll
        for (int u = 0; u < 3; ++u) {
          float b = WTih0[i * G3 + u * 256 + col];
          xw[u][0] += xlo.x * b; xw[u][1] += xlo.y * b;
          xw[u][2] += xlo.z * b; xw[u][3] += xlo.w * b;
          xw[u][4] += xhi.x * b; xw[u][5] += xhi.y * b;
          xw[u][6] += xhi.z * b; xw[u][7] += xhi.w * b;
        }
      }
    } else {
#pragma unroll
      for (int u = 0; u < 3; ++u)
#pragma unroll
        for (int r = 0; r < 8; ++r) exc[u * 8 + r] = gh[u][r];
    }
    __syncthreads();

    if (half == 0) {
      float hn[8];
#pragma unroll
      for (int r = 0; r < 8; ++r) {
        float g0 = gh[0][r] + exc[r];
        float g1 = gh[1][r] + exc[8 + r];
        float g2 = gh[2][r] + exc[16 + r];
        float rr = sigmoidf_(xw[0][r] + (g0 + b_hh0[0]));
        float zz = sigmoidf_(xw[1][r] + (g1 + b_hh0[1]));
        float nn = tanhf(xw[2][r] + rr * (g2 + b_hh0[2]));
        h0c[r] = (1.f - zz) * nn + zz * h0c[r];
        hn[r] = h0c[r];
      }
      *(float4*)&h0nxt[col * 8]     = *(float4*)&hn[0];
      *(float4*)&h0nxt[col * 8 + 4] = *(float4*)&hn[4];
    }
    __syncthreads();

    // ================= layer 1 =================
    float acc[3][8];
#pragma unroll
    for (int u = 0; u < 3; ++u)
#pragma unroll
      for (int r = 0; r < 8; ++r) acc[u][r] = 0.f;
    kloop128(h0nxt + aoff, Bc0, acc);       // x-part (new h0)
    float xn8[8];
#pragma unroll
    for (int r = 0; r < 8; ++r) { xn8[r] = acc[2][r]; acc[2][r] = 0.f; }
    kloop128(h1cur + aoff, Bc1, acc);       // h-part: r/z continue, n fresh

    if (half == 1) {
#pragma unroll
      for (int r = 0; r < 8; ++r) {
        exc[r]      = acc[0][r];
        exc[8 + r]  = acc[1][r];
        exc[16 + r] = xn8[r];
        exc[24 + r] = acc[2][r];
      }
    }
    __syncthreads();

    if (half == 0) {
      float hn[8];
#pragma unroll
      for (int r = 0; r < 8; ++r) {
        float ra = acc[0][r] + exc[r];
        float za = acc[1][r] + exc[8 + r];
        float xa = xn8[r] + exc[16 + r];
        float ha = acc[2][r] + exc[24 + r];
        float rr = sigmoidf_((ra + b_ih1[0]) + b_hh1[0]);
        float zz = sigmoidf_((za + b_ih1[1]) + b_hh1[1]);
        float nn = tanhf((xa + b_ih1[2]) + rr * (ha + b_hh1[2]));
        h1c[r] = (1.f - zz) * nn + zz * h1c[r];
        hn[r] = h1c[r];
      }
      *(float4*)&h1nxt[col * 8]     = *(float4*)&hn[0];
      *(float4*)&h1nxt[col * 8 + 4] = *(float4*)&hn[4];
    }
    __syncthreads();
  }

  if (half == 0) {
#pragma unroll
    for (int r = 0; r < 8; ++r)
      hrow[(size_t)(m0 + r) * 256 + col] = h1c[r];
  }
}

// ---------------------------------------------------------------- generic GEMM
__global__ __launch_bounds__(256, 2)
void gemm_act(const float* __restrict__ A, const int* __restrict__ rowsrc,
              const float* __restrict__ WT, const float* __restrict__ bias,
              float* __restrict__ C, int M, int N, int K, int act)
{
  __shared__ float4 As4[128 * 32];
  const int tx = threadIdx.x, ty = threadIdx.y;
  const int tid = ty * 32 + tx;
  const int n0 = blockIdx.x * 32, m0 = blockIdx.y * 32;
  const int K4 = K >> 2;

  for (int c = tid; c < K4 * 32; c += 256) {
    int k4 = c % K4, m = c / K4;
    int row = m0 + m;
    if (rowsrc) row = rowsrc[row];
    As4[k4 * 32 + m] = *(const float4*)(A + (size_t)row * K + k4 * 4);
  }
  __syncthreads();

  float acc[4] = {0,0,0,0};
  const int n = n0 + tx;
  const float* pb = WT + n;

  float bc[4], bn_[4];
#pragma unroll
  for (int kk = 0; kk < 4; ++kk) bc[kk] = pb[(size_t)kk * N];
  for (int k4 = 0; k4 < K4; ++k4) {
    int nk4 = (k4 + 1 < K4) ? (k4 + 1) : 0;
    const float* pn = pb + (size_t)nk4 * 4 * N;
#pragma unroll
    for (int kk = 0; kk < 4; ++kk) bn_[kk] = pn[(size_t)kk * N];
    float4 a0 = As4[k4 * 32 + ty * 4 + 0];
    float4 a1 = As4[k4 * 32 + ty * 4 + 1];
    float4 a2 = As4[k4 * 32 + ty * 4 + 2];
    float4 a3 = As4[k4 * 32 + ty * 4 + 3];
#pragma unroll
    for (int kk = 0; kk < 4; ++kk) {
      float b = bc[kk];
      acc[0] += ((const float*)&a0)[kk] * b;
      acc[1] += ((const float*)&a1)[kk] * b;
      acc[2] += ((const float*)&a2)[kk] * b;
      acc[3] += ((const float*)&a3)[kk] * b;
    }
#pragma unroll
    for (int q = 0; q < 4; ++q) bc[q] = bn_[q];
  }
  float bb = bias ? bias[n] : 0.f;
#pragma unroll
  for (int r = 0; r < 4; ++r) {
    float v = acc[r] + bb;
    if (act) v = (v >= 0.f) ? v : 0.01f * v;
    C[(size_t)(m0 + ty * 4 + r) * N + n] = v;
  }
}

// ---------------------------------------------------------------- small stages
__global__ void mbday_part(const float* __restrict__ mbf, float* __restrict__ part) {
  int d = blockIdx.x, sl = blockIdx.y, c = threadIdx.x;
  float s = 0.f;
  int base = d * 512 + sl * 64;
  for (int st = 0; st < 64; ++st) s += mbf[(size_t)(base + st) * 256 + c];
  part[(size_t)(d * 8 + sl) * 256 + c] = s;
}

__global__ void mbday_fin(const float* __restrict__ part, float* __restrict__ mbday) {
  int d = blockIdx.x, c = threadIdx.x;
  float s = 0.f;
#pragma unroll
  for (int p = 0; p < 8; ++p) s += part[(size_t)(d * 8 + p) * 256 + c];
  mbday[d * 256 + c] = s * (1.0f / 512.0f);
}

__global__ void daytopk_kernel(const float* __restrict__ mbday, const float* __restrict__ thd,
                               int* __restrict__ dayidx) {
  __shared__ float mbs[256];
  __shared__ float sim[256];
  __shared__ float red[256];
  __shared__ int   redi[256];
  const int d = blockIdx.x, t = threadIdx.x;
  mbs[t] = mbday[d * 256 + t];
  __syncthreads();
  red[t] = mbs[t] * mbs[t];
  __syncthreads();
  for (int o = 128; o; o >>= 1) { if (t < o) red[t] += red[t + o]; __syncthreads(); }
  float xn = sqrtf(red[0]);
  float v = -INFINITY;
  if (t < 240) {
    float dot = 0.f, yn2 = 0.f;
    for (int k = 0; k < 256; ++k) {
      float y = thd[t * 256 + k];
      dot += mbs[k] * y;
      yn2 += y * y;
    }
    float den = xn * sqrtf(yn2);
    v = (den > 0.f) ? dot / den : 0.f;
  }
  sim[t] = v;
  __syncthreads();
  for (int it = 0; it < 10; ++it) {
    red[t] = sim[t]; redi[t] = t;
    __syncthreads();
    for (int o = 128; o; o >>= 1) {
      if (t < o) {
        if (red[t + o] > red[t] || (red[t + o] == red[t] && redi[t + o] < redi[t])) {
          red[t] = red[t + o]; redi[t] = redi[t + o];
        }
      }
      __syncthreads();
    }
    if (t == 0) { int bi = redi[0]; dayidx[d * 10 + it] = bi; sim[bi] = -INFINITY; }
    __syncthreads();
  }
}

__global__ void rowsrc_kernel(const int* __restrict__ dayidx, int* __restrict__ rowsrc) {
  int r = blockIdx.x * 256 + threadIdx.x;
  if (r < NSAMP) rowsrc[r] = dayidx[r >> 9] * 512 + (r & 511);
}

__global__ void rownorm_kernel(const float* __restrict__ X, float* __restrict__ out, int rows) {
  int w = threadIdx.x >> 6;
  int lane = threadIdx.x & 63;
  int row = blockIdx.x * 4 + w;
  if (row >= rows) return;
  float4 x = *(const float4*)(X + (size_t)row * 256 + lane * 4);
  float s = x.x * x.x + x.y * x.y + x.z * x.z + x.w * x.w;
#pragma unroll
  for (int o = 32; o; o >>= 1) s += __shfl_down(s, o, 64);
  if (lane == 0) out[row] = sqrtf(s);
}

__global__ void qnorm_kernel(float* __restrict__ q, const float* __restrict__ qn) {
  int i = blockIdx.x * 256 + threadIdx.x;
  int row = i >> 8;
  float n = qn[row];
  q[i] = (n > 0.f) ? q[i] / n : 0.f;
}

__global__ void khT_kernel(const float* __restrict__ kh, const float* __restrict__ khn,
                           float* __restrict__ khT) {
  __shared__ float tile[32][33];
  int jb = blockIdx.x * 32;
  int kb = blockIdx.y * 32;
  int tx = threadIdx.x & 31, tyy = threadIdx.x >> 5;
  for (int rr = tyy; rr < 32; rr += 8) {
    float n = khn[jb + rr];
    float v = kh[(size_t)(jb + rr) * 256 + kb + tx];
    tile[rr][tx] = (n > 0.f) ? v / n : 0.f;
  }
  __syncthreads();
  for (int rr = tyy; rr < 32; rr += 8) {
    khT[(size_t)(kb + rr) * NSAMP + jb + tx] = tile[tx][rr];
  }
}

// ---------------------------------------------------------------- cs GEMM + top-10 (split, XCD-swizzled)
__global__ __launch_bounds__(256, 4)
void csmax_kernel(const float* __restrict__ qh, const float* __restrict__ khT,
                  float* __restrict__ topvp, int* __restrict__ topip)
{
  __shared__ float4 qs[256][2];
  __shared__ float csch[8 * 512];
  const int tid = threadIdx.x;
  const int split = blockIdx.x & 7;
  const int m0 = (blockIdx.x >> 3) * 8;
  {
    int k = tid;
    float4 v0, v1;
    v0.x = qh[(size_t)(m0 + 0) * 256 + k]; v0.y = qh[(size_t)(m0 + 1) * 256 + k];
    v0.z = qh[(size_t)(m0 + 2) * 256 + k]; v0.w = qh[(size_t)(m0 + 3) * 256 + k];
    v1.x = qh[(size_t)(m0 + 4) * 256 + k]; v1.y = qh[(size_t)(m0 + 5) * 256 + k];
    v1.z = qh[(size_t)(m0 + 6) * 256 + k]; v1.w = qh[(size_t)(m0 + 7) * 256 + k];
    qs[k][0] = v0; qs[k][1] = v1;
  }
  __syncthreads();
  const int lane = tid & 63;
  const int wv = tid >> 6;

  float tv0[10], tv1[10];
  int   tj0[10], tj1[10];
  int   tn0 = 0, tn1 = 0;
  float tmv0 = -INFINITY, tmv1 = -INFINITY;
  int   tmi0 = 0, tmi1 = 0;

  auto process_row = [&](int r, float (&tv)[10], int (&tj)[10], int& tn,
                         float& tmv, int& tmi, int jb) {
    float4 c0 = *(const float4*)&csch[r * 512 + lane * 8];
    float4 c1 = *(const float4*)&csch[r * 512 + lane * 8 + 4];
    float cv[8] = {c0.x, c0.y, c0.z, c0.w, c1.x, c1.y, c1.z, c1.w};
    const int cj0 = jb + lane * 8;
    while (true) {
      float bv = -INFINITY; int bj = 0x7fffffff;
#pragma unroll
      for (int u = 0; u < 8; ++u) {
        if (cv[u] > bv) { bv = cv[u]; bj = cj0 + u; }
      }
#pragma unroll
      for (int o = 32; o; o >>= 1) {
        float ov = __shfl_down(bv, o, 64);
        int   oj = __shfl_down(bj, o, 64);
        if (ov > bv || (ov == bv && oj < bj)) { bv = ov; bj = oj; }
      }
      bv = __shfl(bv, 0, 64); bj = __shfl(bj, 0, 64);
      bool take;
      if (tn < 10) take = true;
      else take = (bv > tmv) || (bv == tmv && bj < tmi);
      if (!take) break;
      if (tn < 10) {
#pragma unroll
        for (int s = 0; s < 10; ++s) if (s == tn) { tv[s] = bv; tj[s] = bj; }
        tn++;
        if (tn == 10) {
          float mv = tv[0]; int mi = tj[0];
#pragma unroll
          for (int s = 1; s < 10; ++s) {
            bool w = (tv[s] < mv) || (tv[s] == mv && tj[s] > mi);
            if (w) { mv = tv[s]; mi = tj[s]; }
          }
          tmv = mv; tmi = mi;
        }
      } else {
        int ms = 0; float mv = tv[0]; int mi = tj[0];
#pragma unroll
        for (int s = 1; s < 10; ++s) {
          bool w = (tv[s] < mv) || (tv[s] == mv && tj[s] > mi);
          if (w) { ms = s; mv = tv[s]; mi = tj[s]; }
        }
#pragma unroll
        for (int s = 0; s < 10; ++s) if (s == ms) { tv[s] = bv; tj[s] = bj; }
        mv = tv[0]; mi = tj[0];
#pragma unroll
        for (int s = 1; s < 10; ++s) {
          bool w = (tv[s] < mv) || (tv[s] == mv && tj[s] > mi);
          if (w) { mv = tv[s]; mi = tj[s]; }
        }
        tmv = mv; tmi = mi;
      }
#pragma unroll
      for (int u = 0; u < 8; ++u) if (cj0 + u == bj) cv[u] = -INFINITY;
    }
  };

  for (int ci = 0; ci < 5; ++ci) {
    const int ch = split * 5 + ci;
    const int jb = ch * 512;
    float acc[8][2];
#pragma unroll
    for (int r = 0; r < 8; ++r) { acc[r][0] = 0.f; acc[r][1] = 0.f; }
    const float* kp = khT + jb + tid;

    float b0c[4], b1c[4], b0n[4], b1n[4];
#pragma unroll
    for (int kk = 0; kk < 4; ++kk) {
      b0c[kk] = kp[(size_t)kk * NSAMP];
      b1c[kk] = kp[(size_t)kk * NSAMP + 256];
    }
    for (int k4 = 0; k4 < 64; ++k4) {
      int nk4 = (k4 + 1) & 63;
      const float* pn = kp + (size_t)nk4 * 4 * NSAMP;
#pragma unroll
      for (int kk = 0; kk < 4; ++kk) {
        b0n[kk] = pn[(size_t)kk * NSAMP];
        b1n[kk] = pn[(size_t)kk * NSAMP + 256];
      }
#pragma unroll
      for (int kk = 0; kk < 4; ++kk) {
        float4 qa = qs[k4 * 4 + kk][0];
        float4 qb = qs[k4 * 4 + kk][1];
        float b0 = b0c[kk], b1 = b1c[kk];
        acc[0][0] += qa.x * b0; acc[1][0] += qa.y * b0; acc[2][0] += qa.z * b0; acc[3][0] += qa.w * b0;
        acc[4][0] += qb.x * b0; acc[5][0] += qb.y * b0; acc[6][0] += qb.z * b0; acc[7][0] += qb.w * b0;
        acc[0][1] += qa.x * b1; acc[1][1] += qa.y * b1; acc[2][1] += qa.z * b1; acc[3][1] += qa.w * b1;
        acc[4][1] += qb.x * b1; acc[5][1] += qb.y * b1; acc[6][1] += qb.z * b1; acc[7][1] += qb.w * b1;
      }
#pragma unroll
      for (int q = 0; q < 4; ++q) { b0c[q] = b0n[q]; b1c[q] = b1n[q]; }
    }
    __syncthreads();
#pragma unroll
    for (int r = 0; r < 8; ++r) {
      csch[r * 512 + tid] = acc[r][0];
      csch[r * 512 + 256 + tid] = acc[r][1];
    }
    __syncthreads();
    process_row(wv,     tv0, tj0, tn0, tmv0, tmi0, jb);
    process_row(wv + 4, tv1, tj1, tn1, tmv1, tmi1, jb);
  }
  __syncthreads();

  if (lane == 0) {
    int row0 = m0 + wv;
#pragma unroll
    for (int s = 0; s < 10; ++s) {
      topvp[(size_t)row0 * 80 + split * 10 + s] = tv0[s];
      topip[(size_t)row0 * 80 + split * 10 + s] = tj0[s];
    }
    int row1 = m0 + wv + 4;
#pragma unroll
    for (int s = 0; s < 10; ++s) {
      topvp[(size_t)row1 * 80 + split * 10 + s] = tv1[s];
      topip[(size_t)row1 * 80 + split * 10 + s] = tj1[s];
    }
  }
}

// merge 8 splits x 10 candidates -> global top-10 per row (value desc, idx asc)
__global__ void merge_topk(const float* __restrict__ topvp, const int* __restrict__ topip,
                           float* __restrict__ topv, int* __restrict__ topi)
{
  const int wv = threadIdx.x >> 6;
  const int lane = threadIdx.x & 63;
  const int row = blockIdx.x * 4 + wv;
  float v0 = topvp[(size_t)row * 80 + lane];
  int   i0 = topip[(size_t)row * 80 + lane];
  float v1 = (lane < 16) ? topvp[(size_t)row * 80 + 64 + lane] : -INFINITY;
  int   i1 = (lane < 16) ? topip[(size_t)row * 80 + 64 + lane] : 0x7fffffff;
  for (int s = 0; s < 10; ++s) {
    float bv = v0; int bj = i0;
    if (v1 > bv || (v1 == bv && i1 < bj)) { bv = v1; bj = i1; }
#pragma unroll
    for (int o = 1; o < 64; o <<= 1) {
      float ov = __shfl_xor(bv, o, 64);
      int   oj = __shfl_xor(bj, o, 64);
      if (ov > bv || (ov == bv && oj < bj)) { bv = ov; bj = oj; }
    }
    if (lane == 0) { topv[row * 10 + s] = bv; topi[row * 10 + s] = bj; }
    if (i0 == bj) { v0 = -INFINITY; i0 = 0x7fffffff; }
    if (i1 == bj) { v1 = -INFINITY; i1 = 0x7fffffff; }
  }
}

// ---------------------------------------------------------------- final: agg + fc
__global__ void final_kernel(const float* __restrict__ mb, const float* __restrict__ kh,
                             const float* __restrict__ topv, const int* __restrict__ topi,
                             const float* __restrict__ fcW, const float* __restrict__ fcb,
                             float* __restrict__ y)
{
  __shared__ float red[256];
  int n = blockIdx.x, c = threadIdx.x;
  float agg = 0.f;
#pragma unroll
  for (int k = 0; k < 10; ++k) {
    float w = topv[n * 10 + k] / 10.0f;
    int idx = topi[n * 10 + k];
    agg += w * kh[(size_t)idx * 256 + c];
  }
  float val = fcW[c] * mb[(size_t)n * 256 + c] + fcW[256 + c] * agg;
  red[c] = val;
  __syncthreads();
  for (int o = 128; o; o >>= 1) { if (c < o) red[c] += red[c + o]; __syncthreads(); }
  if (c == 0) y[n] = red[0] + fcb[0];
}

// ---------------------------------------------------------------- launch
extern "C" void kernel_launch(void* const* d_in, const int* in_sizes, int n_in,
                              void* d_out, int out_size, void* d_ws, size_t ws_size,
                              hipStream_t stream)
{
  const float* inp    = (const float*)d_in[0];
  const float* trainh = (const float*)d_in[1];
  const float* thd    = (const float*)d_in[2];
  const float* Wih0   = (const float*)d_in[3];
  const float* Whh0   = (const float*)d_in[4];
  const float* bih0   = (const float*)d_in[5];
  const float* bhh0   = (const float*)d_in[6];
  const float* Wih1   = (const float*)d_in[7];
  const float* Whh1   = (const float*)d_in[8];
  const float* bih1   = (const float*)d_in[9];
  const float* bhh1   = (const float*)d_in[10];
  const float* lin0W  = (const float*)d_in[11];
  const float* lin0b  = (const float*)d_in[12];
  const float* lin1W  = (const float*)d_in[13];
  const float* lin1b  = (const float*)d_in[14];
  const float* lin2W  = (const float*)d_in[15];
  const float* lin2b  = (const float*)d_in[16];
  const float* p1W    = (const float*)d_in[17];
  const float* p2W    = (const float*)d_in[18];
  const float* fcW    = (const float*)d_in[19];
  const float* fcb    = (const float*)d_in[20];

  float* ws = (float*)d_ws;
  float* WT_hh0 = ws + 0;          // 256x768
  float* WTcat  = ws + 196608;     // 512x768
  float* WT_l0  = ws + 589824;     // 256x512
  float* WT_l1  = ws + 720896;     // 512x512
  float* WT_l2  = ws + 983040;     // 512x256
  float* WT_p1  = ws + 1114112;    // 256x256
  float* WT_p2  = ws + 1179648;    // 256x256
  float* hrow   = ws + 1245184;    // 2048x256
  float* mb1    = ws + 3342336;    // 2048x512 (reused for topk candidates)
  float* mb2    = ws + 4390912;    // 2048x512 (WT_ih0 during GRU; mbday partials later)
  float* mbf    = ws + 5439488;    // 2048x256
  float* mbday  = ws + 5963776;    // 4x256
  float* qbuf   = ws + 5964800;    // 2048x256
  float* kh     = ws + 6489088;    // 20480x256
  float* khT    = ws + 11731968;   // 256x20480 (normalized)
  float* khn    = ws + 16974848;   // 20480
  float* qn     = ws + 16995328;   // 2048
  float* topv   = ws + 16997376;   // 2048x10
  int*   dayidx = (int*)(ws + 17017856);
  int*   rowsrc = (int*)(ws + 17017920);
  int*   topi   = (int*)(ws + 17038400);
  float* topvp  = mb1;                       // 2048x80
  int*   topip  = (int*)(mb1 + 163840);      // 2048x80
  float* WT_ih0 = mb2;                       // 6x768 (used only during gru_fused)
  float* mbpart = mb2;                       // 4x8x256 (after GRU)

  PrepArgs pa;
  pa.src[0] = Whh0;  pa.dst[0] = WT_hh0; pa.N[0] = 768; pa.K[0] = 256; pa.ro[0] = 0;
  pa.src[1] = Wih1;  pa.dst[1] = WTcat;  pa.N[1] = 768; pa.K[1] = 256; pa.ro[1] = 0;
  pa.src[2] = Whh1;  pa.dst[2] = WTcat;  pa.N[2] = 768; pa.K[2] = 256; pa.ro[2] = 256;
  pa.src[3] = lin0W; pa.dst[3] = WT_l0;  pa.N[3] = 512; pa.K[3] = 256; pa.ro[3] = 0;
  pa.src[4] = lin1W; pa.dst[4] = WT_l1;  pa.N[4] = 512; pa.K[4] = 512; pa.ro[4] = 0;
  pa.src[5] = lin2W; pa.dst[5] = WT_l2;  pa.N[5] = 256; pa.K[5] = 512; pa.ro[5] = 0;
  pa.src[6] = p1W;   pa.dst[6] = WT_p1;  pa.N[6] = 256; pa.K[6] = 256; pa.ro[6] = 0;
  pa.src[7] = p2W;   pa.dst[7] = WT_p2;  pa.N[7] = 256; pa.K[7] = 256; pa.ro[7] = 0;
  pa.src[8] = Wih0;  pa.dst[8] = WT_ih0; pa.N[8] = 768; pa.K[8] = 6;   pa.ro[8] = 0;
  prep_weights<<<dim3(64, 9), dim3(256), 0, stream>>>(pa);

  gru_fused<<<256, 512, 0, stream>>>(inp, WT_hh0, WTcat, WT_ih0, bih0, bhh0, bih1, bhh1, hrow);

  gemm_act<<<dim3(16, 64), dim3(32, 8), 0, stream>>>(hrow, nullptr, WT_l0, lin0b, mb1, 2048, 512, 256, 1);
  gemm_act<<<dim3(16, 64), dim3(32, 8), 0, stream>>>(mb1, nullptr, WT_l1, lin1b, mb2, 2048, 512, 512, 1);
  gemm_act<<<dim3(8, 64),  dim3(32, 8), 0, stream>>>(mb2, nullptr, WT_l2, lin2b, mbf, 2048, 256, 512, 1);

  mbday_part<<<dim3(4, 8), 256, 0, stream>>>(mbf, mbpart);
  mbday_fin<<<4, 256, 0, stream>>>(mbpart, mbday);
  daytopk_kernel<<<4, 256, 0, stream>>>(mbday, thd, dayidx);
  rowsrc_kernel<<<80, 256, 0, stream>>>(dayidx, rowsrc);

  gemm_act<<<dim3(8, 640), dim3(32, 8), 0, stream>>>(trainh, rowsrc, WT_p2, nullptr, kh, 20480, 256, 256, 0);
  gemm_act<<<dim3(8, 64),  dim3(32, 8), 0, stream>>>(mbf, nullptr, WT_p1, nullptr, qbuf, 2048, 256, 256, 0);

  rownorm_kernel<<<5120, 256, 0, stream>>>(kh, khn, 20480);
  rownorm_kernel<<<512, 256, 0, stream>>>(qbuf, qn, 2048);
  qnorm_kernel<<<2048, 256, 0, stream>>>(qbuf, qn);
  khT_kernel<<<dim3(640, 8), 256, 0, stream>>>(kh, khn, khT);

  csmax_kernel<<<2048, 256, 0, stream>>>(qbuf, khT, topvp, topip);
  merge_topk<<<512, 256, 0, stream>>>(topvp, topip, topv, topi);
  final_kernel<<<2048, 256, 0, stream>>>(mbf, kh, topv, topi, fcW, fcb, (float*)d_out);

  (void)in_sizes; (void)n_in; (void)out_size; (void)ws_size;
}